// Round 1
// 22752.843 us; speedup vs baseline: 1.4793x; 1.4793x over previous
//
#include <hip/hip_runtime.h>
#include <cstdint>
#include <cstddef>
#include <cmath>

// ---------------------------------------------------------------------------
// LiveSAL round 4: conv re-tiled to 128co x 121px blocks (wave = 64co x 64px,
// 16 MFMA per weight fetch, no redundant z-staging), q/k/v and ek/ev convs
// fused into single dispatches (Cout=768 / 512), LN vectorized to float4.
// Attention/GRU/elementwise math identical to the verified R2/R3 code.
// ---------------------------------------------------------------------------

#define Sn 5
#define Bn 128
#define Cn 256
#define Nn 121          // 11*11
#define HEADSn 8
#define NITERn 2
#define EPSf 1e-5f
#define SCALEf 0.0625f  // 256^-0.5
#define CHWn (Cn*Nn)    // 30976

static const size_t SLICEsz = (size_t)Bn*CHWn;       // 3,964,928 floats
static const size_t FULLsz  = (size_t)Sn*SLICEsz;    // 19,824,640 floats
static const size_t SLA     = SLICEsz + 1024;        // padded slice arena

typedef __attribute__((ext_vector_type(8))) short short8;
typedef __attribute__((ext_vector_type(4))) float f32x4;

static __device__ __forceinline__ short f2bf(float f){
  union { float f; unsigned u; } x; x.f = f;
  unsigned r = (x.u + 0x7FFFu + ((x.u >> 16) & 1u)) >> 16;   // RNE
  return (short)r;
}

// ---------------------------------------------------------------------------
// Weight prep: fp32 [Cout][Cin][3][3] -> bf16 [Cout][9][Cinp] (zero-padded K).
// grid = (Cout, 9), block = 128.
// ---------------------------------------------------------------------------
__global__ __launch_bounds__(128) void wprep_kernel(
    const float* __restrict__ w, short* __restrict__ o, int Cin, int Cinp)
{
  const int co = blockIdx.x, tap = blockIdx.y;
  short* orow = o + ((size_t)co*9 + tap)*Cinp;
  const float* wrow = w + (size_t)co*Cin*9 + tap;
  for (int ci = threadIdx.x; ci < Cinp; ci += 128)
    orow[ci] = (ci < Cin) ? f2bf(wrow[(size_t)ci*9]) : (short)0;
}

// ---------------------------------------------------------------------------
// MFMA conv3x3, pad=1, 11x11. One sample per block.x; block = 4 waves,
// block tile 128co x 128px (121 valid, no z split), wave tile 64co x 64px.
// 16x16x32 bf16 MFMA; 16 MFMAs amortize each group of 4 weight loads.
// A (weights) loaded straight from global bf16 [co][tap][Cinp] (k-contig).
// B (activations) staged per 128-ci group into LDS [px][ci] bf16 (stride 136,
// rows 121..127 zeroed = tap-shift OOB sentinel).
// Input may be a channel-concat of inA (cinA ch) + inB; mMode adds the
// m-conv extra channels (256=tc0, 257=tc1, 258=rpe row).
// ---------------------------------------------------------------------------
__global__ __launch_bounds__(256) void conv_mfma_kernel(
    const float* __restrict__ inA, const float* __restrict__ inB,
    int cinA, int Cin, int Cinp, int Cout,
    const short* __restrict__ wbf, const float* __restrict__ bias,
    float* __restrict__ out,
    int mMode, float tc0, float tc1, const float* __restrict__ rp)
{
  __shared__ short Xs[128*136];
  const int samp = blockIdx.x;
  const int coB  = blockIdx.y * 128;
  const int t    = threadIdx.x;
  const int lane = t & 63;
  const int wv   = t >> 6;
  const int wy   = wv >> 1;      // co 64-half within block
  const int wx   = wv & 1;       // px 64-half within block
  const int l15  = lane & 15;
  const int quad = lane >> 4;

  int nout[4], py[4], pxx[4];
  #pragma unroll
  for (int ns = 0; ns < 4; ++ns){
    nout[ns] = wx*64 + ns*16 + l15;
    py[ns]  = nout[ns] / 11;
    pxx[ns] = nout[ns] % 11;
  }

  f32x4 acc[4][4];
  #pragma unroll
  for (int ms = 0; ms < 4; ++ms)
    #pragma unroll
    for (int ns = 0; ns < 4; ++ns) acc[ms][ns] = (f32x4){0.f,0.f,0.f,0.f};

  const float* baseA = inA + (size_t)samp*(size_t)cinA*Nn;
  const float* baseB = inB ? inB + (size_t)samp*(size_t)(Cin-cinA)*Nn : nullptr;

  const int ngrp = (Cin + 127) >> 7;
  for (int grp = 0; grp < ngrp; ++grp){
    __syncthreads();
    // ---- stage 128 ci x 128 px into LDS as bf16 [px][ci] ----
    for (int e = t; e < 128*128; e += 256){
      const int px = e & 127, cil = e >> 7;
      const int ci = grp*128 + cil;
      float v = 0.f;
      if (px < Nn && ci < Cin){
        if (mMode && ci >= 256)
          v = (ci == 256) ? tc0 : (ci == 257) ? tc1 : rp[px];
        else if (ci < cinA) v = baseA[(size_t)ci*Nn + px];
        else                v = baseB[(size_t)(ci-cinA)*Nn + px];
      }
      Xs[px*136 + cil] = f2bf(v);
    }
    __syncthreads();

    const int rem = Cin - grp*128;
    const int nkc = (rem >= 128) ? 4 : ((rem + 31) >> 5);

    for (int tap = 0; tap < 9; ++tap){
      const int dy = tap/3 - 1, dx = tap%3 - 1;
      int pp[4];
      #pragma unroll
      for (int ns = 0; ns < 4; ++ns){
        const int yy = py[ns] + dy, xx = pxx[ns] + dx;
        const bool ok = (nout[ns] < Nn) && yy >= 0 && yy < 11 && xx >= 0 && xx < 11;
        pp[ns] = ok ? yy*11 + xx : Nn;   // row 121 = zero sentinel
      }
      const short* wb0 = wbf + ((size_t)(coB + wy*64 + l15)*9 + tap)*Cinp
                             + grp*128 + quad*8;
      for (int kc = 0; kc < nkc; ++kc){
        short8 a[4], b[4];
        #pragma unroll
        for (int ms = 0; ms < 4; ++ms)
          a[ms] = *(const short8*)(wb0 + (size_t)ms*16*9*Cinp + kc*32);
        #pragma unroll
        for (int ns = 0; ns < 4; ++ns)
          b[ns] = *(const short8*)(&Xs[pp[ns]*136 + kc*32 + quad*8]);
        #pragma unroll
        for (int ms = 0; ms < 4; ++ms)
          #pragma unroll
          for (int ns = 0; ns < 4; ++ns)
            acc[ms][ns] = __builtin_amdgcn_mfma_f32_16x16x32_bf16(
                              a[ms], b[ns], acc[ms][ns], 0, 0, 0);
      }
    }
  }

  // ---- epilogue: C layout col=lane&15 (n), row=quad*4+r (m) ----
  #pragma unroll
  for (int ms = 0; ms < 4; ++ms)
    #pragma unroll
    for (int ns = 0; ns < 4; ++ns){
      const int n = nout[ns];
      if (n < Nn){
        const int mbase = coB + wy*64 + ms*16 + quad*4;
        #pragma unroll
        for (int r = 0; r < 4; ++r)
          out[((size_t)samp*Cout + mbase + r)*Nn + n] = acc[ms][ns][r] + bias[mbase + r];
      }
    }
}

// ---------------------------------------------------------------------------
// LayerNorm over (C,H,W) per sample. out = alpha*maybe_relu(LN(x)*g+b)+addend
// float4-vectorized (CHWn = 30976 = 7744 float4s, all bases 16B aligned).
// ---------------------------------------------------------------------------
__global__ __launch_bounds__(256) void ln_kernel(
    const float* __restrict__ x, const float* __restrict__ g, const float* __restrict__ bb,
    float* __restrict__ out, const float* __restrict__ alpha,
    const float* __restrict__ addend, int relu)
{
  const size_t base = (size_t)blockIdx.x * CHWn;
  const f32x4* xs = (const f32x4*)(x + base);
  const int NV = CHWn/4;   // 7744
  float sum = 0.f, ss = 0.f;
  for (int i = threadIdx.x; i < NV; i += 256){
    f32x4 v = xs[i];
    sum += v.x + v.y + v.z + v.w;
    ss  += v.x*v.x + v.y*v.y + v.z*v.z + v.w*v.w;
  }
  #pragma unroll
  for (int o = 32; o > 0; o >>= 1){ sum += __shfl_down(sum, o, 64); ss += __shfl_down(ss, o, 64); }
  __shared__ float r1[4], r2[4];
  const int wid = threadIdx.x >> 6;
  if ((threadIdx.x & 63) == 0){ r1[wid] = sum; r2[wid] = ss; }
  __syncthreads();
  sum = r1[0]+r1[1]+r1[2]+r1[3];
  ss  = r2[0]+r2[1]+r2[2]+r2[3];
  const float mean = sum * (1.f/CHWn);
  const float var  = ss * (1.f/CHWn) - mean*mean;
  const float inv  = rsqrtf(var + EPSf);
  const float a = alpha ? *alpha : 1.f;
  const f32x4* gv = (const f32x4*)g;
  const f32x4* bv = (const f32x4*)bb;
  const f32x4* av = addend ? (const f32x4*)(addend + base) : nullptr;
  f32x4* ov = (f32x4*)(out + base);
  for (int i = threadIdx.x; i < NV; i += 256){
    f32x4 v = (xs[i] - mean) * inv * gv[i] + bv[i];
    if (relu){ v.x=fmaxf(v.x,0.f); v.y=fmaxf(v.y,0.f); v.z=fmaxf(v.z,0.f); v.w=fmaxf(v.w,0.f); }
    v *= a;
    if (av) v += av[i];
    ov[i] = v;
  }
}

// ---------------------------------------------------------------------------
// Fused attention per (sample, head) — verified R2 fp32 kernel, with runtime
// channel strides so q / k / v may live in packed multi-conv outputs.
// ---------------------------------------------------------------------------
template<int HDt, int CPT, int NPASS>
__global__ __launch_bounds__(256) void attn_kernel(
    const float* __restrict__ q, const float* __restrict__ k, const float* __restrict__ v,
    float* __restrict__ o, int qs, int ks, int os)
{
  __shared__ float T[Nn*132];
  const int nh_ = Cn / HDt;
  const int samp = blockIdx.x / nh_;
  const int hh = blockIdx.x % nh_;
  const size_t qoff  = ((size_t)samp*qs + hh*HDt)*Nn;
  const size_t kvoff = ((size_t)samp*ks + hh*HDt)*Nn;
  const size_t ooff  = ((size_t)samp*os + hh*HDt)*Nn;
  const int t = threadIdx.x;
  {
    const int tn = t >> 4, tm = t & 15;
    const int n0 = tn*8, m0 = tm*8;
    float acc[8][8];
    #pragma unroll
    for (int a2=0;a2<8;a2++)
      #pragma unroll
      for (int b2=0;b2<8;b2++) acc[a2][b2] = 0.f;
    const float* qp = q + qoff + n0;
    const float* kp = k + kvoff + m0;
    #pragma unroll 2
    for (int d=0; d<HDt; ++d){
      float qv[8], kv[8];
      #pragma unroll
      for (int j2=0;j2<8;j2++){ qv[j2] = qp[d*Nn + j2]; kv[j2] = kp[d*Nn + j2]; }
      #pragma unroll
      for (int a2=0;a2<8;a2++)
        #pragma unroll
        for (int b2=0;b2<8;b2++) acc[a2][b2] = fmaf(qv[a2], kv[b2], acc[a2][b2]);
    }
    #pragma unroll
    for (int b2=0;b2<8;b2++){
      const int m = m0 + b2;
      if (m < Nn){
        #pragma unroll
        for (int a2=0;a2<8;a2++) T[m*132 + n0 + a2] = acc[a2][b2] * SCALEf;
      }
    }
  }
  __syncthreads();
  if (t < Nn){
    float mx = -1e30f;
    for (int m2=0;m2<Nn;m2++) mx = fmaxf(mx, T[m2*132+t]);
    float sum = 0.f;
    for (int m2=0;m2<Nn;m2++){ float e = __expf(T[m2*132+t]-mx); sum += e; T[m2*132+t] = e; }
    const float invs = 1.f/sum;
    for (int m2=0;m2<Nn;m2++) T[m2*132+t] *= invs;
  }
  __syncthreads();
  {
    const int ng_ = t & 15, cg = t >> 4;
    const int an0 = ng_*8;
    for (int pass=0; pass<NPASS; ++pass){
      const int c0 = pass*64 + cg*CPT;
      float av[CPT][8];
      #pragma unroll
      for (int ci2=0;ci2<CPT;ci2++)
        #pragma unroll
        for (int j2=0;j2<8;j2++) av[ci2][j2] = 0.f;
      for (int m2=0;m2<Nn;m2++){
        float tv[8];
        #pragma unroll
        for (int j2=0;j2<8;j2++) tv[j2] = T[m2*132 + an0 + j2];
        #pragma unroll
        for (int ci2=0;ci2<CPT;ci2++){
          const float vv = v[kvoff + (size_t)(c0+ci2)*Nn + m2];
          #pragma unroll
          for (int j2=0;j2<8;j2++) av[ci2][j2] = fmaf(vv, tv[j2], av[ci2][j2]);
        }
      }
      #pragma unroll
      for (int ci2=0;ci2<CPT;ci2++){
        float* op = o + ooff + (size_t)(c0+ci2)*Nn + an0;
        #pragma unroll
        for (int j2=0;j2<8;j2++) if (an0+j2 < Nn) op[j2] = av[ci2][j2];
      }
    }
  }
}

// Spatial mean per (local sample, channel). grid=(Bn,32).
__global__ __launch_bounds__(128) void mean_kernel(const float* __restrict__ x, float* __restrict__ out)
{
  const int s = blockIdx.x; const int c0 = blockIdx.y*8;
  __shared__ float r[2];
  for (int cc=0; cc<8; ++cc){
    const int c = c0+cc;
    float v = 0.f;
    if (threadIdx.x < Nn) v = x[((size_t)s*Cn + c)*Nn + threadIdx.x];
    #pragma unroll
    for (int o=32;o>0;o>>=1) v += __shfl_down(v, o, 64);
    if ((threadIdx.x & 63) == 0) r[threadIdx.x>>6] = v;
    __syncthreads();
    if (threadIdx.x == 0) out[(size_t)s*Cn + c] = (r[0]+r[1]) * (1.f/Nn);
    __syncthreads();
  }
}

// gate[b,c] = sigmoid( gw[c,:] . [meanX(b); meanM(b)] + gb[c] )
__global__ __launch_bounds__(256) void gate_kernel(
    const float* __restrict__ meanX, const float* __restrict__ meanM,
    const float* __restrict__ gw, const float* __restrict__ gb,
    float* __restrict__ gate)
{
  const int b = blockIdx.x;
  __shared__ float mv[512];
  mv[threadIdx.x]     = meanX[(size_t)b*Cn + threadIdx.x];
  mv[256+threadIdx.x] = meanM[(size_t)b*Cn + threadIdx.x];
  __syncthreads();
  const float* gr = gw + (size_t)threadIdx.x*512;
  float acc = gb[threadIdx.x];
  for (int k2=0;k2<512;k2++) acc = fmaf(gr[k2], mv[k2], acc);
  gate[(size_t)b*Cn + threadIdx.x] = 1.f/(1.f+__expf(-acc));
}

// out (+)= msg * gate
__global__ __launch_bounds__(256) void accum_kernel(
    const float* __restrict__ msg, const float* __restrict__ gate,
    float* __restrict__ outs, int init)
{
  const size_t idx = (size_t)blockIdx.x*256 + threadIdx.x;
  if (idx >= SLICEsz) return;
  const size_t t_ = idx / Nn;
  const int c = (int)(t_ & 255);
  const int b = (int)(t_ >> 8);
  const float v = msg[idx] * gate[(size_t)b*Cn + c];
  outs[idx] = init ? v : (outs[idx] + v);
}

// hi = iia*hi + (1-iia)*outi
__global__ __launch_bounds__(256) void comb_kernel(float* __restrict__ hi,
    const float* __restrict__ outi, const float* __restrict__ iia)
{
  const size_t idx = (size_t)blockIdx.x*256 + threadIdx.x;
  if (idx >= SLICEsz) return;
  const float a = *iia;
  hi[idx] = a*hi[idx] + (1.f-a)*outi[idx];
}

// rh = sigmoid(zrq[:,256:512]) * h
__global__ __launch_bounds__(256) void rh_kernel(const float* __restrict__ zrq,
    const float* __restrict__ h, float* __restrict__ rh)
{
  const size_t idx = (size_t)blockIdx.x*256 + threadIdx.x;
  if (idx >= SLICEsz) return;
  const int n_ = (int)(idx % Nn);
  const size_t t_ = idx / Nn;
  const int c = (int)(t_ & 255);
  const size_t s = t_ >> 8;
  float r = zrq[(s*512 + 256 + c)*Nn + n_];
  r = 1.f/(1.f+__expf(-r));
  rh[idx] = r*h[idx];
}

// nh = (1-z)*h + z*tanh(hq) + h
__global__ __launch_bounds__(256) void nh_kernel(const float* __restrict__ zrq,
    const float* __restrict__ hq, const float* __restrict__ h,
    float* __restrict__ nh)
{
  const size_t idx = (size_t)blockIdx.x*256 + threadIdx.x;
  if (idx >= SLICEsz) return;
  const int n_ = (int)(idx % Nn);
  const size_t t_ = idx / Nn;
  const int c = (int)(t_ & 255);
  const size_t s = t_ >> 8;
  float z = zrq[(s*512 + c)*Nn + n_];
  z = 1.f/(1.f+__expf(-z));
  const float hv = h[idx];
  nh[idx] = (1.f-z)*hv + z*tanhf(hq[idx]) + hv;
}

// ---------------------------------------------------------------------------
// Host orchestration
// ---------------------------------------------------------------------------
static const int PJ[5][4] = {{1,2,0,0},{0,2,3,0},{0,1,3,4},{1,2,4,0},{2,3,0,0}};
static const int PNP[5]   = {2,3,4,3,2};

extern "C" void kernel_launch(void* const* d_in, const int* in_sizes, int n_in,
                              void* d_out, int out_size, void* d_ws, size_t ws_size,
                              hipStream_t stream)
{
  (void)in_sizes; (void)n_in; (void)out_size;
  const float* x   = (const float*)d_in[0];
  const float* ing = (const float*)d_in[1];
  const float* inb = (const float*)d_in[2];
  const float* iqw = (const float*)d_in[3];
  const float* iqb = (const float*)d_in[4];
  const float* ikw = (const float*)d_in[5];
  const float* ikb = (const float*)d_in[6];
  const float* ivw = (const float*)d_in[7];
  const float* ivb = (const float*)d_in[8];
  const float* iow = (const float*)d_in[9];
  const float* iob = (const float*)d_in[10];
  const float* iong= (const float*)d_in[11];
  const float* ionb= (const float*)d_in[12];
  const float* ia  = (const float*)d_in[13];
  const float* eng = (const float*)d_in[14];
  const float* enb = (const float*)d_in[15];
  const float* rpe = (const float*)d_in[16];
  const float* mw  = (const float*)d_in[17];
  const float* mb  = (const float*)d_in[18];
  const float* eqw = (const float*)d_in[19];
  const float* eqb = (const float*)d_in[20];
  const float* ekw = (const float*)d_in[21];
  const float* ekb = (const float*)d_in[22];
  const float* evw = (const float*)d_in[23];
  const float* evb = (const float*)d_in[24];
  const float* gw  = (const float*)d_in[25];
  const float* gb  = (const float*)d_in[26];
  const float* eow = (const float*)d_in[27];
  const float* eob = (const float*)d_in[28];
  const float* eong= (const float*)d_in[29];
  const float* eonb= (const float*)d_in[30];
  const float* iia = (const float*)d_in[31];
  const float* zrw = (const float*)d_in[32];
  const float* zrb = (const float*)d_in[33];
  const float* hww = (const float*)d_in[34];
  const float* hwb = (const float*)d_in[35];
  const float* ng  = (const float*)d_in[36];
  const float* nbg = (const float*)d_in[37];

  // ---- workspace layout (floats) ----
  float* W = (float*)d_ws;
  size_t off = 0;
  float* h      = W + off; off += FULLsz + 1024;          // persistent state
  float* qkv    = W + off; off += 3*SLICEsz + 1024;       // qkv / kv / zrq / io-out / eo-out
  float* p2     = W + off; off += SLA;                    // attn out / y / msg
  float* xsl    = W + off; off += SLA;                    // xn / rh / nh
  float* qsl    = W + off; off += SLA;                    // q (eq) / hq
  float* osl    = W + off; off += SLA;                    // inter accumulation
  float* meanXb = W + off; off += Bn*Cn;
  float* meanM  = W + off; off += Bn*Cn;
  float* gateb  = W + off; off += Bn*Cn;
  float* bqkv   = W + off; off += 768;                    // concat bias q|k|v
  float* bekv   = W + off; off += 512;                    // concat bias ek|ev
  // bf16 weight buffers (shorts), allocated on float boundary
  short* WB = (short*)(W + off);
  size_t so = 0;
  short* iqB = WB + so; so += (size_t)256*9*256;          // iq|ik|iv contiguous
  short* ikB = WB + so; so += (size_t)256*9*256;
  short* ivB = WB + so; so += (size_t)256*9*256;
  short* ioB = WB + so; so += (size_t)256*9*256;
  short* eqB = WB + so; so += (size_t)256*9*256;
  short* ekB = WB + so; so += (size_t)256*9*256;          // ek|ev contiguous
  short* evB = WB + so; so += (size_t)256*9*256;
  short* eoB = WB + so; so += (size_t)256*9*256;
  short* mB_ = WB + so; so += (size_t)256*9*384;
  short* zrB = WB + so; so += (size_t)512*9*512;
  short* hwB = WB + so; so += (size_t)256*9*512;
  off += (so + 1) / 2;
  if (ws_size < off * sizeof(float)) return;              // diagnostic guard

  float* hi = (float*)d_out;                              // full arena: intra out / comb

  hipMemcpyAsync(h, x, FULLsz*sizeof(float), hipMemcpyDeviceToDevice, stream);
  // concat biases for fused convs
  hipMemcpyAsync(bqkv,     iqb, 256*sizeof(float), hipMemcpyDeviceToDevice, stream);
  hipMemcpyAsync(bqkv+256, ikb, 256*sizeof(float), hipMemcpyDeviceToDevice, stream);
  hipMemcpyAsync(bqkv+512, ivb, 256*sizeof(float), hipMemcpyDeviceToDevice, stream);
  hipMemcpyAsync(bekv,     ekb, 256*sizeof(float), hipMemcpyDeviceToDevice, stream);
  hipMemcpyAsync(bekv+256, evb, 256*sizeof(float), hipMemcpyDeviceToDevice, stream);

  // ---- weight prep (once per call; ~18 MB of bf16) ----
  wprep_kernel<<<dim3(256,9),128,0,stream>>>(iqw, iqB, 256, 256);
  wprep_kernel<<<dim3(256,9),128,0,stream>>>(ikw, ikB, 256, 256);
  wprep_kernel<<<dim3(256,9),128,0,stream>>>(ivw, ivB, 256, 256);
  wprep_kernel<<<dim3(256,9),128,0,stream>>>(iow, ioB, 256, 256);
  wprep_kernel<<<dim3(256,9),128,0,stream>>>(eqw, eqB, 256, 256);
  wprep_kernel<<<dim3(256,9),128,0,stream>>>(ekw, ekB, 256, 256);
  wprep_kernel<<<dim3(256,9),128,0,stream>>>(evw, evB, 256, 256);
  wprep_kernel<<<dim3(256,9),128,0,stream>>>(eow, eoB, 256, 256);
  wprep_kernel<<<dim3(256,9),128,0,stream>>>(mw,  mB_, 259, 384);
  wprep_kernel<<<dim3(512,9),128,0,stream>>>(zrw, zrB, 512, 512);
  wprep_kernel<<<dim3(256,9),128,0,stream>>>(hww, hwB, 512, 512);

  const int gridSlc = (int)(SLICEsz / 256);   // 15,488 exact

  // conv helper: regular conv (no m-extras), grid (samples, Cout/128)
  #define CONV(inA_, inB_, cinA_, Cin_, Cinp_, Cout_, wb_, bi_, out_)            \
    conv_mfma_kernel<<<dim3(Bn, (Cout_)/128), 256, 0, stream>>>(                 \
        inA_, inB_, cinA_, Cin_, Cinp_, Cout_, wb_, bi_, out_, 0, 0.f, 0.f, nullptr)

  for (int it = 0; it < NITERn; ++it){
    // ---------------- intra_all (per slice) ----------------
    for (int s = 0; s < Sn; ++s){
      const float* hs = h + (size_t)s*SLICEsz;
      ln_kernel<<<Bn,256,0,stream>>>(hs, ing, inb, xsl, nullptr, nullptr, 0);
      CONV(xsl, nullptr, 256, 256, 256, 768, iqB, bqkv, qkv);                    // q|k|v
      attn_kernel<256,4,4><<<Bn,256,0,stream>>>(qkv, qkv + (size_t)256*Nn,
                                                qkv + (size_t)512*Nn, p2,
                                                768, 768, 256);
      CONV(p2, nullptr, 256, 256, 256, 256, ioB, iob, qkv);                      // io-out
      ln_kernel<<<Bn,256,0,stream>>>(qkv, iong, ionb, hi + (size_t)s*SLICEsz, ia, xsl, 1);
    }

    // ---------------- inter (per i, per pair) ----------------
    for (int i = 0; i < Sn; ++i){
      ln_kernel<<<Bn,256,0,stream>>>(h + (size_t)i*SLICEsz, eng, enb, xsl, nullptr, nullptr, 0);
      CONV(xsl, nullptr, 256, 256, 256, 256, eqB, eqb, qsl);
      mean_kernel<<<dim3(Bn,32),128,0,stream>>>(xsl, meanXb);
      const int np = PNP[i];
      for (int pl = 0; pl < np; ++pl){
        const int j = PJ[i][pl];
        const float tc0 = (i < j) ? 1.f : -1.f;
        const float tc1 = fabsf((float)(i - j)) * 0.5f;
        const int ri = (((i - j + 1) % 4) + 4) % 4;
        conv_mfma_kernel<<<dim3(Bn,2),256,0,stream>>>(
            h + (size_t)j*SLICEsz, nullptr, 256, 259, 384, 256, mB_, mb, p2,
            1, tc0, tc1, rpe + (size_t)ri*Nn);                                   // y
        CONV(p2, nullptr, 256, 256, 256, 512, ekB, bekv, qkv);                   // k|v
        attn_kernel<32,2,1><<<Bn*HEADSn,256,0,stream>>>(qsl, qkv,
                                                qkv + (size_t)256*Nn, p2,
                                                256, 512, 256);                  // msg_raw
        CONV(p2, nullptr, 256, 256, 256, 256, eoB, eob, qkv);
        ln_kernel<<<Bn,256,0,stream>>>(qkv, eong, eonb, p2, nullptr, nullptr, 1);// msg
        mean_kernel<<<dim3(Bn,32),128,0,stream>>>(p2, meanM);
        gate_kernel<<<Bn,256,0,stream>>>(meanXb, meanM, gw, gb, gateb);
        accum_kernel<<<gridSlc,256,0,stream>>>(p2, gateb, osl, pl == 0);
      }
      comb_kernel<<<gridSlc,256,0,stream>>>(hi + (size_t)i*SLICEsz, osl, iia);   // hi=comb
    }

    // ---------------- GRU + final LN (per slice) ----------------
    for (int s = 0; s < Sn; ++s){
      const float* hs = h + (size_t)s*SLICEsz;
      float* cs = hi + (size_t)s*SLICEsz;   // comb
      CONV(cs, hs, 256, 512, 512, 512, zrB, zrb, qkv);                           // zrq
      rh_kernel<<<gridSlc,256,0,stream>>>(qkv, hs, xsl);                         // xsl = r*h
      CONV(cs, xsl, 256, 512, 512, 256, hwB, hwb, p2);                           // hq
      nh_kernel<<<gridSlc,256,0,stream>>>(qkv, p2, hs, xsl);                     // xsl = nh
      float* dst = (it == NITERn-1) ? cs : (h + (size_t)s*SLICEsz);
      ln_kernel<<<Bn,256,0,stream>>>(xsl, ng, nbg, dst, nullptr, nullptr, 0);
    }
  }
  #undef CONV
}

// Round 2
// 17257.571 us; speedup vs baseline: 1.9504x; 1.3184x over previous
//
#include <hip/hip_runtime.h>
#include <cstdint>
#include <cstddef>
#include <cmath>

// ---------------------------------------------------------------------------
// LiveSAL round 5: conv occupancy + A-load coalescing.
//  - conv blocks now 8 waves (512 thr), wave tile 64co x 32px (R3-verified
//    fragment mapping), 2+ waves/SIMD for latency hiding.
//  - weights pre-packed in MFMA-fragment order: each A fragment load is one
//    coalesced 1KB dwordx4 (was 64-line scatter).
//  - kc inner loop compile-time unrolled for full 128-ci groups.
//  - gw transposed once so gate dot-product loads coalesce.
// Everything else (LN/attn/GRU elementwise) identical to verified R4 code.
// ---------------------------------------------------------------------------

#define Sn 5
#define Bn 128
#define Cn 256
#define Nn 121          // 11*11
#define HEADSn 8
#define NITERn 2
#define EPSf 1e-5f
#define SCALEf 0.0625f  // 256^-0.5
#define CHWn (Cn*Nn)    // 30976

static const size_t SLICEsz = (size_t)Bn*CHWn;       // 3,964,928 floats
static const size_t FULLsz  = (size_t)Sn*SLICEsz;    // 19,824,640 floats
static const size_t SLA     = SLICEsz + 1024;        // padded slice arena

typedef __attribute__((ext_vector_type(8))) short short8;
typedef __attribute__((ext_vector_type(4))) float f32x4;

static __device__ __forceinline__ short f2bf(float f){
  union { float f; unsigned u; } x; x.f = f;
  unsigned r = (x.u + 0x7FFFu + ((x.u >> 16) & 1u)) >> 16;   // RNE
  return (short)r;
}

// ---------------------------------------------------------------------------
// Weight prep: fp32 [Cout][Cin][3][3] -> bf16 fragment-ordered
//   AW[coH][grp][tap][kc][ms][lane][8],  lane = quad*16+l15
// where co = coH*64 + ms*16 + l15, ci = grp*128 + kc*32 + quad*8 + e.
// Strides (shorts): grp=73728 (=9*8192), tap=8192, kc=2048, ms=512.
// Zero-padded over ci in [Cin, Cinp). grid = (Cout, 9), block = 128.
// ---------------------------------------------------------------------------
__global__ __launch_bounds__(128) void wprep_kernel(
    const float* __restrict__ w, short* __restrict__ o, int Cin, int Cinp)
{
  const int co = blockIdx.x, tap = blockIdx.y;
  const int G = Cinp >> 7;
  const int coH = co >> 6, ms = (co >> 4) & 3, l15 = co & 15;
  const float* wrow = w + (size_t)co*Cin*9 + tap;
  short* obase = o + (size_t)coH*G*73728 + (size_t)tap*8192 + ms*512 + l15*8;
  for (int ci = threadIdx.x; ci < Cinp; ci += 128){
    const int grp = ci >> 7, kc = (ci >> 5) & 3, quad = (ci >> 3) & 3, e = ci & 7;
    const short val = (ci < Cin) ? f2bf(wrow[(size_t)ci*9]) : (short)0;
    obase[(size_t)grp*73728 + kc*2048 + quad*128 + e] = val;
  }
}

// gw [256][512] fp32 -> gwT [512][256]
__global__ __launch_bounds__(256) void gwt_kernel(
    const float* __restrict__ gw, float* __restrict__ gwT)
{
  const int k = blockIdx.x, c = threadIdx.x;
  gwT[(size_t)k*256 + c] = gw[(size_t)c*512 + k];
}

// ---------------------------------------------------------------------------
// MFMA conv3x3, pad=1, 11x11. One sample per block.x; block = 8 waves (512),
// block tile 128co x 128px (121 valid), wave tile 64co x 32px.
// A (weights) from fragment-ordered global bf16 (coalesced 1KB loads).
// B (activations) staged per 128-ci group into LDS [px][ci] bf16 (stride 136,
// rows 121..127 zeroed = tap-shift OOB sentinel).
// Input may be channel-concat of inA (cinA ch) + inB; mMode adds the m-conv
// extra channels (256=tc0, 257=tc1, 258=rpe row).
// ---------------------------------------------------------------------------
__global__ __launch_bounds__(512) void conv_mfma_kernel(
    const float* __restrict__ inA, const float* __restrict__ inB,
    int cinA, int Cin, int Cinp, int Cout,
    const short* __restrict__ wbf, const float* __restrict__ bias,
    float* __restrict__ out,
    int mMode, float tc0, float tc1, const float* __restrict__ rp)
{
  __shared__ short Xs[128*136];
  const int samp = blockIdx.x;
  const int coB  = blockIdx.y * 128;
  const int t    = threadIdx.x;
  const int lane = t & 63;
  const int wv   = t >> 6;       // 0..7
  const int wy   = wv >> 2;      // co 64-half within block
  const int wx   = wv & 3;       // px 32-quarter within block
  const int l15  = lane & 15;
  const int quad = lane >> 4;
  const int G    = Cinp >> 7;

  int nout[2], py[2], pxx[2];
  #pragma unroll
  for (int ns = 0; ns < 2; ++ns){
    nout[ns] = wx*32 + ns*16 + l15;
    py[ns]  = nout[ns] / 11;
    pxx[ns] = nout[ns] % 11;
  }

  f32x4 acc[4][2];
  #pragma unroll
  for (int ms = 0; ms < 4; ++ms)
    #pragma unroll
    for (int ns = 0; ns < 2; ++ns) acc[ms][ns] = (f32x4){0.f,0.f,0.f,0.f};

  const float* baseA = inA + (size_t)samp*(size_t)cinA*Nn;
  const float* baseB = inB ? inB + (size_t)samp*(size_t)(Cin-cinA)*Nn : nullptr;

  // per-wave weight base: coH = blockIdx.y*2 + wy, + lane offset folded in
  const short* wgbase = wbf + (size_t)(blockIdx.y*2 + wy)*G*73728 + lane*8;

  const int ngrp = (Cin + 127) >> 7;
  for (int grp = 0; grp < ngrp; ++grp){
    __syncthreads();
    // ---- stage 128 ci x 128 px into LDS as bf16 [px][ci] ----
    for (int e = t; e < 128*128; e += 512){
      const int px = e & 127, cil = e >> 7;
      const int ci = grp*128 + cil;
      float v = 0.f;
      if (px < Nn && ci < Cin){
        if (mMode && ci >= 256)
          v = (ci == 256) ? tc0 : (ci == 257) ? tc1 : rp[px];
        else if (ci < cinA) v = baseA[(size_t)ci*Nn + px];
        else                v = baseB[(size_t)(ci-cinA)*Nn + px];
      }
      Xs[px*136 + cil] = f2bf(v);
    }
    __syncthreads();

    const int rem = Cin - grp*128;
    const short* wgrp = wgbase + (size_t)grp*73728;

    if (rem >= 128){
      for (int tap = 0; tap < 9; ++tap){
        const int dy = tap/3 - 1, dx = tap%3 - 1;
        int pp[2];
        #pragma unroll
        for (int ns = 0; ns < 2; ++ns){
          const int yy = py[ns] + dy, xx = pxx[ns] + dx;
          const bool ok = (nout[ns] < Nn) && yy >= 0 && yy < 11 && xx >= 0 && xx < 11;
          pp[ns] = ok ? yy*11 + xx : Nn;   // row 121 = zero sentinel
        }
        const short* wb = wgrp + tap*8192;
        #pragma unroll
        for (int kc = 0; kc < 4; ++kc){
          short8 a[4], b[2];
          #pragma unroll
          for (int ms = 0; ms < 4; ++ms)
            a[ms] = *(const short8*)(wb + kc*2048 + ms*512);
          #pragma unroll
          for (int ns = 0; ns < 2; ++ns)
            b[ns] = *(const short8*)(&Xs[pp[ns]*136 + kc*32 + quad*8]);
          #pragma unroll
          for (int ms = 0; ms < 4; ++ms)
            #pragma unroll
            for (int ns = 0; ns < 2; ++ns)
              acc[ms][ns] = __builtin_amdgcn_mfma_f32_16x16x32_bf16(
                                a[ms], b[ns], acc[ms][ns], 0, 0, 0);
        }
      }
    } else {
      const int nkc = (rem + 31) >> 5;
      for (int tap = 0; tap < 9; ++tap){
        const int dy = tap/3 - 1, dx = tap%3 - 1;
        int pp[2];
        #pragma unroll
        for (int ns = 0; ns < 2; ++ns){
          const int yy = py[ns] + dy, xx = pxx[ns] + dx;
          const bool ok = (nout[ns] < Nn) && yy >= 0 && yy < 11 && xx >= 0 && xx < 11;
          pp[ns] = ok ? yy*11 + xx : Nn;
        }
        const short* wb = wgrp + tap*8192;
        for (int kc = 0; kc < nkc; ++kc){
          short8 a[4], b[2];
          #pragma unroll
          for (int ms = 0; ms < 4; ++ms)
            a[ms] = *(const short8*)(wb + kc*2048 + ms*512);
          #pragma unroll
          for (int ns = 0; ns < 2; ++ns)
            b[ns] = *(const short8*)(&Xs[pp[ns]*136 + kc*32 + quad*8]);
          #pragma unroll
          for (int ms = 0; ms < 4; ++ms)
            #pragma unroll
            for (int ns = 0; ns < 2; ++ns)
              acc[ms][ns] = __builtin_amdgcn_mfma_f32_16x16x32_bf16(
                                a[ms], b[ns], acc[ms][ns], 0, 0, 0);
        }
      }
    }
  }

  // ---- epilogue: C layout col=lane&15 (n), row=quad*4+r (m) ----
  #pragma unroll
  for (int ms = 0; ms < 4; ++ms)
    #pragma unroll
    for (int ns = 0; ns < 2; ++ns){
      const int n = nout[ns];
      if (n < Nn){
        const int mbase = coB + wy*64 + ms*16 + quad*4;
        #pragma unroll
        for (int r = 0; r < 4; ++r)
          out[((size_t)samp*Cout + mbase + r)*Nn + n] = acc[ms][ns][r] + bias[mbase + r];
      }
    }
}

// ---------------------------------------------------------------------------
// LayerNorm over (C,H,W) per sample. out = alpha*maybe_relu(LN(x)*g+b)+addend
// ---------------------------------------------------------------------------
__global__ __launch_bounds__(256) void ln_kernel(
    const float* __restrict__ x, const float* __restrict__ g, const float* __restrict__ bb,
    float* __restrict__ out, const float* __restrict__ alpha,
    const float* __restrict__ addend, int relu)
{
  const size_t base = (size_t)blockIdx.x * CHWn;
  const f32x4* xs = (const f32x4*)(x + base);
  const int NV = CHWn/4;   // 7744
  float sum = 0.f, ss = 0.f;
  for (int i = threadIdx.x; i < NV; i += 256){
    f32x4 v = xs[i];
    sum += v.x + v.y + v.z + v.w;
    ss  += v.x*v.x + v.y*v.y + v.z*v.z + v.w*v.w;
  }
  #pragma unroll
  for (int o = 32; o > 0; o >>= 1){ sum += __shfl_down(sum, o, 64); ss += __shfl_down(ss, o, 64); }
  __shared__ float r1[4], r2[4];
  const int wid = threadIdx.x >> 6;
  if ((threadIdx.x & 63) == 0){ r1[wid] = sum; r2[wid] = ss; }
  __syncthreads();
  sum = r1[0]+r1[1]+r1[2]+r1[3];
  ss  = r2[0]+r2[1]+r2[2]+r2[3];
  const float mean = sum * (1.f/CHWn);
  const float var  = ss * (1.f/CHWn) - mean*mean;
  const float inv  = rsqrtf(var + EPSf);
  const float a = alpha ? *alpha : 1.f;
  const f32x4* gv = (const f32x4*)g;
  const f32x4* bv = (const f32x4*)bb;
  const f32x4* av = addend ? (const f32x4*)(addend + base) : nullptr;
  f32x4* ov = (f32x4*)(out + base);
  for (int i = threadIdx.x; i < NV; i += 256){
    f32x4 v = (xs[i] - mean) * inv * gv[i] + bv[i];
    if (relu){ v.x=fmaxf(v.x,0.f); v.y=fmaxf(v.y,0.f); v.z=fmaxf(v.z,0.f); v.w=fmaxf(v.w,0.f); }
    v *= a;
    if (av) v += av[i];
    ov[i] = v;
  }
}

// ---------------------------------------------------------------------------
// Fused attention per (sample, head) — verified fp32 kernel, runtime strides.
// ---------------------------------------------------------------------------
template<int HDt, int CPT, int NPASS>
__global__ __launch_bounds__(256) void attn_kernel(
    const float* __restrict__ q, const float* __restrict__ k, const float* __restrict__ v,
    float* __restrict__ o, int qs, int ks, int os)
{
  __shared__ float T[Nn*132];
  const int nh_ = Cn / HDt;
  const int samp = blockIdx.x / nh_;
  const int hh = blockIdx.x % nh_;
  const size_t qoff  = ((size_t)samp*qs + hh*HDt)*Nn;
  const size_t kvoff = ((size_t)samp*ks + hh*HDt)*Nn;
  const size_t ooff  = ((size_t)samp*os + hh*HDt)*Nn;
  const int t = threadIdx.x;
  {
    const int tn = t >> 4, tm = t & 15;
    const int n0 = tn*8, m0 = tm*8;
    float acc[8][8];
    #pragma unroll
    for (int a2=0;a2<8;a2++)
      #pragma unroll
      for (int b2=0;b2<8;b2++) acc[a2][b2] = 0.f;
    const float* qp = q + qoff + n0;
    const float* kp = k + kvoff + m0;
    #pragma unroll 2
    for (int d=0; d<HDt; ++d){
      float qv[8], kv[8];
      #pragma unroll
      for (int j2=0;j2<8;j2++){ qv[j2] = qp[d*Nn + j2]; kv[j2] = kp[d*Nn + j2]; }
      #pragma unroll
      for (int a2=0;a2<8;a2++)
        #pragma unroll
        for (int b2=0;b2<8;b2++) acc[a2][b2] = fmaf(qv[a2], kv[b2], acc[a2][b2]);
    }
    #pragma unroll
    for (int b2=0;b2<8;b2++){
      const int m = m0 + b2;
      if (m < Nn){
        #pragma unroll
        for (int a2=0;a2<8;a2++) T[m*132 + n0 + a2] = acc[a2][b2] * SCALEf;
      }
    }
  }
  __syncthreads();
  if (t < Nn){
    float mx = -1e30f;
    for (int m2=0;m2<Nn;m2++) mx = fmaxf(mx, T[m2*132+t]);
    float sum = 0.f;
    for (int m2=0;m2<Nn;m2++){ float e = __expf(T[m2*132+t]-mx); sum += e; T[m2*132+t] = e; }
    const float invs = 1.f/sum;
    for (int m2=0;m2<Nn;m2++) T[m2*132+t] *= invs;
  }
  __syncthreads();
  {
    const int ng_ = t & 15, cg = t >> 4;
    const int an0 = ng_*8;
    for (int pass=0; pass<NPASS; ++pass){
      const int c0 = pass*64 + cg*CPT;
      float av[CPT][8];
      #pragma unroll
      for (int ci2=0;ci2<CPT;ci2++)
        #pragma unroll
        for (int j2=0;j2<8;j2++) av[ci2][j2] = 0.f;
      for (int m2=0;m2<Nn;m2++){
        float tv[8];
        #pragma unroll
        for (int j2=0;j2<8;j2++) tv[j2] = T[m2*132 + an0 + j2];
        #pragma unroll
        for (int ci2=0;ci2<CPT;ci2++){
          const float vv = v[kvoff + (size_t)(c0+ci2)*Nn + m2];
          #pragma unroll
          for (int j2=0;j2<8;j2++) av[ci2][j2] = fmaf(vv, tv[j2], av[ci2][j2]);
        }
      }
      #pragma unroll
      for (int ci2=0;ci2<CPT;ci2++){
        float* op = o + ooff + (size_t)(c0+ci2)*Nn + an0;
        #pragma unroll
        for (int j2=0;j2<8;j2++) if (an0+j2 < Nn) op[j2] = av[ci2][j2];
      }
    }
  }
}

// Spatial mean per (local sample, channel). grid=(Bn,32).
__global__ __launch_bounds__(128) void mean_kernel(const float* __restrict__ x, float* __restrict__ out)
{
  const int s = blockIdx.x; const int c0 = blockIdx.y*8;
  __shared__ float r[2];
  for (int cc=0; cc<8; ++cc){
    const int c = c0+cc;
    float v = 0.f;
    if (threadIdx.x < Nn) v = x[((size_t)s*Cn + c)*Nn + threadIdx.x];
    #pragma unroll
    for (int o=32;o>0;o>>=1) v += __shfl_down(v, o, 64);
    if ((threadIdx.x & 63) == 0) r[threadIdx.x>>6] = v;
    __syncthreads();
    if (threadIdx.x == 0) out[(size_t)s*Cn + c] = (r[0]+r[1]) * (1.f/Nn);
    __syncthreads();
  }
}

// gate[b,c] = sigmoid( gwT[:,c] . [meanX(b); meanM(b)] + gb[c] ), coalesced
__global__ __launch_bounds__(256) void gate_kernel(
    const float* __restrict__ meanX, const float* __restrict__ meanM,
    const float* __restrict__ gwT, const float* __restrict__ gb,
    float* __restrict__ gate)
{
  const int b = blockIdx.x;
  __shared__ float mv[512];
  mv[threadIdx.x]     = meanX[(size_t)b*Cn + threadIdx.x];
  mv[256+threadIdx.x] = meanM[(size_t)b*Cn + threadIdx.x];
  __syncthreads();
  float acc = gb[threadIdx.x];
  for (int k2=0;k2<512;k2++) acc = fmaf(gwT[(size_t)k2*256 + threadIdx.x], mv[k2], acc);
  gate[(size_t)b*Cn + threadIdx.x] = 1.f/(1.f+__expf(-acc));
}

// out (+)= msg * gate
__global__ __launch_bounds__(256) void accum_kernel(
    const float* __restrict__ msg, const float* __restrict__ gate,
    float* __restrict__ outs, int init)
{
  const size_t idx = (size_t)blockIdx.x*256 + threadIdx.x;
  if (idx >= SLICEsz) return;
  const size_t t_ = idx / Nn;
  const int c = (int)(t_ & 255);
  const int b = (int)(t_ >> 8);
  const float v = msg[idx] * gate[(size_t)b*Cn + c];
  outs[idx] = init ? v : (outs[idx] + v);
}

// hi = iia*hi + (1-iia)*outi
__global__ __launch_bounds__(256) void comb_kernel(float* __restrict__ hi,
    const float* __restrict__ outi, const float* __restrict__ iia)
{
  const size_t idx = (size_t)blockIdx.x*256 + threadIdx.x;
  if (idx >= SLICEsz) return;
  const float a = *iia;
  hi[idx] = a*hi[idx] + (1.f-a)*outi[idx];
}

// rh = sigmoid(zrq[:,256:512]) * h
__global__ __launch_bounds__(256) void rh_kernel(const float* __restrict__ zrq,
    const float* __restrict__ h, float* __restrict__ rh)
{
  const size_t idx = (size_t)blockIdx.x*256 + threadIdx.x;
  if (idx >= SLICEsz) return;
  const int n_ = (int)(idx % Nn);
  const size_t t_ = idx / Nn;
  const int c = (int)(t_ & 255);
  const size_t s = t_ >> 8;
  float r = zrq[(s*512 + 256 + c)*Nn + n_];
  r = 1.f/(1.f+__expf(-r));
  rh[idx] = r*h[idx];
}

// nh = (1-z)*h + z*tanh(hq) + h
__global__ __launch_bounds__(256) void nh_kernel(const float* __restrict__ zrq,
    const float* __restrict__ hq, const float* __restrict__ h,
    float* __restrict__ nh)
{
  const size_t idx = (size_t)blockIdx.x*256 + threadIdx.x;
  if (idx >= SLICEsz) return;
  const int n_ = (int)(idx % Nn);
  const size_t t_ = idx / Nn;
  const int c = (int)(t_ & 255);
  const size_t s = t_ >> 8;
  float z = zrq[(s*512 + c)*Nn + n_];
  z = 1.f/(1.f+__expf(-z));
  const float hv = h[idx];
  nh[idx] = (1.f-z)*hv + z*tanhf(hq[idx]) + hv;
}

// ---------------------------------------------------------------------------
// Host orchestration
// ---------------------------------------------------------------------------
static const int PJ[5][4] = {{1,2,0,0},{0,2,3,0},{0,1,3,4},{1,2,4,0},{2,3,0,0}};
static const int PNP[5]   = {2,3,4,3,2};

extern "C" void kernel_launch(void* const* d_in, const int* in_sizes, int n_in,
                              void* d_out, int out_size, void* d_ws, size_t ws_size,
                              hipStream_t stream)
{
  (void)in_sizes; (void)n_in; (void)out_size;
  const float* x   = (const float*)d_in[0];
  const float* ing = (const float*)d_in[1];
  const float* inb = (const float*)d_in[2];
  const float* iqw = (const float*)d_in[3];
  const float* iqb = (const float*)d_in[4];
  const float* ikw = (const float*)d_in[5];
  const float* ikb = (const float*)d_in[6];
  const float* ivw = (const float*)d_in[7];
  const float* ivb = (const float*)d_in[8];
  const float* iow = (const float*)d_in[9];
  const float* iob = (const float*)d_in[10];
  const float* iong= (const float*)d_in[11];
  const float* ionb= (const float*)d_in[12];
  const float* ia  = (const float*)d_in[13];
  const float* eng = (const float*)d_in[14];
  const float* enb = (const float*)d_in[15];
  const float* rpe = (const float*)d_in[16];
  const float* mw  = (const float*)d_in[17];
  const float* mb  = (const float*)d_in[18];
  const float* eqw = (const float*)d_in[19];
  const float* eqb = (const float*)d_in[20];
  const float* ekw = (const float*)d_in[21];
  const float* ekb = (const float*)d_in[22];
  const float* evw = (const float*)d_in[23];
  const float* evb = (const float*)d_in[24];
  const float* gw  = (const float*)d_in[25];
  const float* gb  = (const float*)d_in[26];
  const float* eow = (const float*)d_in[27];
  const float* eob = (const float*)d_in[28];
  const float* eong= (const float*)d_in[29];
  const float* eonb= (const float*)d_in[30];
  const float* iia = (const float*)d_in[31];
  const float* zrw = (const float*)d_in[32];
  const float* zrb = (const float*)d_in[33];
  const float* hww = (const float*)d_in[34];
  const float* hwb = (const float*)d_in[35];
  const float* ng  = (const float*)d_in[36];
  const float* nbg = (const float*)d_in[37];

  // ---- workspace layout (floats) ----
  float* W = (float*)d_ws;
  size_t off = 0;
  float* h      = W + off; off += FULLsz + 1024;          // persistent state
  float* qkv    = W + off; off += 3*SLICEsz + 1024;       // qkv / kv / zrq / io-out / eo-out
  float* p2     = W + off; off += SLA;                    // attn out / y / msg
  float* xsl    = W + off; off += SLA;                    // xn / rh / nh
  float* qsl    = W + off; off += SLA;                    // q (eq) / hq
  float* osl    = W + off; off += SLA;                    // inter accumulation
  float* meanXb = W + off; off += Bn*Cn;
  float* meanM  = W + off; off += Bn*Cn;
  float* gateb  = W + off; off += Bn*Cn;
  float* bqkv   = W + off; off += 768;                    // concat bias q|k|v
  float* bekv   = W + off; off += 512;                    // concat bias ek|ev
  float* gwT    = W + off; off += 512*256;                // transposed gate weight
  // bf16 weight buffers (shorts), allocated on float boundary
  short* WB = (short*)(W + off);
  size_t so = 0;
  short* iqB = WB + so; so += (size_t)256*9*256;          // iq|ik|iv contiguous
  short* ikB = WB + so; so += (size_t)256*9*256;
  short* ivB = WB + so; so += (size_t)256*9*256;
  short* ioB = WB + so; so += (size_t)256*9*256;
  short* eqB = WB + so; so += (size_t)256*9*256;
  short* ekB = WB + so; so += (size_t)256*9*256;          // ek|ev contiguous
  short* evB = WB + so; so += (size_t)256*9*256;
  short* eoB = WB + so; so += (size_t)256*9*256;
  short* mB_ = WB + so; so += (size_t)256*9*384;
  short* zrB = WB + so; so += (size_t)512*9*512;
  short* hwB = WB + so; so += (size_t)256*9*512;
  off += (so + 1) / 2;
  if (ws_size < off * sizeof(float)) return;              // diagnostic guard

  float* hi = (float*)d_out;                              // full arena: intra out / comb

  hipMemcpyAsync(h, x, FULLsz*sizeof(float), hipMemcpyDeviceToDevice, stream);
  // concat biases for fused convs
  hipMemcpyAsync(bqkv,     iqb, 256*sizeof(float), hipMemcpyDeviceToDevice, stream);
  hipMemcpyAsync(bqkv+256, ikb, 256*sizeof(float), hipMemcpyDeviceToDevice, stream);
  hipMemcpyAsync(bqkv+512, ivb, 256*sizeof(float), hipMemcpyDeviceToDevice, stream);
  hipMemcpyAsync(bekv,     ekb, 256*sizeof(float), hipMemcpyDeviceToDevice, stream);
  hipMemcpyAsync(bekv+256, evb, 256*sizeof(float), hipMemcpyDeviceToDevice, stream);

  // ---- weight prep (once per call; ~18 MB of bf16) ----
  // Each sub-weight is a whole number of 64-co panels, so packing each with
  // its own base yields the fused coH-major layout for fused dispatches.
  wprep_kernel<<<dim3(256,9),128,0,stream>>>(iqw, iqB, 256, 256);
  wprep_kernel<<<dim3(256,9),128,0,stream>>>(ikw, ikB, 256, 256);
  wprep_kernel<<<dim3(256,9),128,0,stream>>>(ivw, ivB, 256, 256);
  wprep_kernel<<<dim3(256,9),128,0,stream>>>(iow, ioB, 256, 256);
  wprep_kernel<<<dim3(256,9),128,0,stream>>>(eqw, eqB, 256, 256);
  wprep_kernel<<<dim3(256,9),128,0,stream>>>(ekw, ekB, 256, 256);
  wprep_kernel<<<dim3(256,9),128,0,stream>>>(evw, evB, 256, 256);
  wprep_kernel<<<dim3(256,9),128,0,stream>>>(eow, eoB, 256, 256);
  wprep_kernel<<<dim3(256,9),128,0,stream>>>(mw,  mB_, 259, 384);
  wprep_kernel<<<dim3(512,9),128,0,stream>>>(zrw, zrB, 512, 512);
  wprep_kernel<<<dim3(256,9),128,0,stream>>>(hww, hwB, 512, 512);
  gwt_kernel<<<512,256,0,stream>>>(gw, gwT);

  const int gridSlc = (int)(SLICEsz / 256);   // 15,488 exact

  // conv helper: regular conv (no m-extras), grid (samples, Cout/128), 512 thr
  #define CONV(inA_, inB_, cinA_, Cin_, Cinp_, Cout_, wb_, bi_, out_)            \
    conv_mfma_kernel<<<dim3(Bn, (Cout_)/128), 512, 0, stream>>>(                 \
        inA_, inB_, cinA_, Cin_, Cinp_, Cout_, wb_, bi_, out_, 0, 0.f, 0.f, nullptr)

  for (int it = 0; it < NITERn; ++it){
    // ---------------- intra_all (per slice) ----------------
    for (int s = 0; s < Sn; ++s){
      const float* hs = h + (size_t)s*SLICEsz;
      ln_kernel<<<Bn,256,0,stream>>>(hs, ing, inb, xsl, nullptr, nullptr, 0);
      CONV(xsl, nullptr, 256, 256, 256, 768, iqB, bqkv, qkv);                    // q|k|v
      attn_kernel<256,4,4><<<Bn,256,0,stream>>>(qkv, qkv + (size_t)256*Nn,
                                                qkv + (size_t)512*Nn, p2,
                                                768, 768, 256);
      CONV(p2, nullptr, 256, 256, 256, 256, ioB, iob, qkv);                      // io-out
      ln_kernel<<<Bn,256,0,stream>>>(qkv, iong, ionb, hi + (size_t)s*SLICEsz, ia, xsl, 1);
    }

    // ---------------- inter (per i, per pair) ----------------
    for (int i = 0; i < Sn; ++i){
      ln_kernel<<<Bn,256,0,stream>>>(h + (size_t)i*SLICEsz, eng, enb, xsl, nullptr, nullptr, 0);
      CONV(xsl, nullptr, 256, 256, 256, 256, eqB, eqb, qsl);
      mean_kernel<<<dim3(Bn,32),128,0,stream>>>(xsl, meanXb);
      const int np = PNP[i];
      for (int pl = 0; pl < np; ++pl){
        const int j = PJ[i][pl];
        const float tc0 = (i < j) ? 1.f : -1.f;
        const float tc1 = fabsf((float)(i - j)) * 0.5f;
        const int ri = (((i - j + 1) % 4) + 4) % 4;
        conv_mfma_kernel<<<dim3(Bn,2),512,0,stream>>>(
            h + (size_t)j*SLICEsz, nullptr, 256, 259, 384, 256, mB_, mb, p2,
            1, tc0, tc1, rpe + (size_t)ri*Nn);                                   // y
        CONV(p2, nullptr, 256, 256, 256, 512, ekB, bekv, qkv);                   // k|v
        attn_kernel<32,2,1><<<Bn*HEADSn,256,0,stream>>>(qsl, qkv,
                                                qkv + (size_t)256*Nn, p2,
                                                256, 512, 256);                  // msg_raw
        CONV(p2, nullptr, 256, 256, 256, 256, eoB, eob, qkv);
        ln_kernel<<<Bn,256,0,stream>>>(qkv, eong, eonb, p2, nullptr, nullptr, 1);// msg
        mean_kernel<<<dim3(Bn,32),128,0,stream>>>(p2, meanM);
        gate_kernel<<<Bn,256,0,stream>>>(meanXb, meanM, gwT, gb, gateb);
        accum_kernel<<<gridSlc,256,0,stream>>>(p2, gateb, osl, pl == 0);
      }
      comb_kernel<<<gridSlc,256,0,stream>>>(hi + (size_t)i*SLICEsz, osl, iia);   // hi=comb
    }

    // ---------------- GRU + final LN (per slice) ----------------
    for (int s = 0; s < Sn; ++s){
      const float* hs = h + (size_t)s*SLICEsz;
      float* cs = hi + (size_t)s*SLICEsz;   // comb
      CONV(cs, hs, 256, 512, 512, 512, zrB, zrb, qkv);                           // zrq
      rh_kernel<<<gridSlc,256,0,stream>>>(qkv, hs, xsl);                         // xsl = r*h
      CONV(cs, xsl, 256, 512, 512, 256, hwB, hwb, p2);                           // hq
      nh_kernel<<<gridSlc,256,0,stream>>>(qkv, p2, hs, xsl);                     // xsl = nh
      float* dst = (it == NITERn-1) ? cs : (h + (size_t)s*SLICEsz);
      ln_kernel<<<Bn,256,0,stream>>>(xsl, ng, nbg, dst, nullptr, nullptr, 0);
    }
  }
  #undef CONV
}

// Round 5
// 15353.114 us; speedup vs baseline: 2.1923x; 1.1240x over previous
//
#include <hip/hip_runtime.h>
#include <cstdint>
#include <cstddef>
#include <cmath>

// ---------------------------------------------------------------------------
// LiveSAL round 7 (bisect): R5-verified conv staging (synchronous slow-stage)
// + R6 host-side pair/slice batching only. The register-prefetch async
// staging (R6 half B) is reverted pending a clean verdict on half A.
// ---------------------------------------------------------------------------

#define Sn 5
#define Bn 128
#define Cn 256
#define Nn 121          // 11*11
#define HEADSn 8
#define NITERn 2
#define EPSf 1e-5f
#define SCALEf 0.0625f  // 256^-0.5
#define CHWn (Cn*Nn)    // 30976

static const size_t SLICEsz = (size_t)Bn*CHWn;       // 3,964,928 floats
static const size_t FULLsz  = (size_t)Sn*SLICEsz;    // 19,824,640 floats
static const size_t SLA     = SLICEsz + 1024;        // padded slice arena

typedef __attribute__((ext_vector_type(8))) short short8;
typedef __attribute__((ext_vector_type(4))) float f32x4;

static __device__ __forceinline__ short f2bf(float f){
  union { float f; unsigned u; } x; x.f = f;
  unsigned r = (x.u + 0x7FFFu + ((x.u >> 16) & 1u)) >> 16;   // RNE
  return (short)r;
}

// ---------------------------------------------------------------------------
// Weight prep: fp32 [Cout][Cin][3][3] -> bf16 fragment-ordered
//   AW[coH][grp][tap][kc][ms][lane][8],  lane = quad*16+l15
// where co = coH*64 + ms*16 + l15, ci = grp*128 + kc*32 + quad*8 + e.
// Strides (shorts): grp=73728 (=9*8192), tap=8192, kc=2048, ms=512.
// ---------------------------------------------------------------------------
__global__ __launch_bounds__(128) void wprep_kernel(
    const float* __restrict__ w, short* __restrict__ o, int Cin, int Cinp)
{
  const int co = blockIdx.x, tap = blockIdx.y;
  const int G = Cinp >> 7;
  const int coH = co >> 6, ms = (co >> 4) & 3, l15 = co & 15;
  const float* wrow = w + (size_t)co*Cin*9 + tap;
  short* obase = o + (size_t)coH*G*73728 + (size_t)tap*8192 + ms*512 + l15*8;
  for (int ci = threadIdx.x; ci < Cinp; ci += 128){
    const int grp = ci >> 7, kc = (ci >> 5) & 3, quad = (ci >> 3) & 3, e = ci & 7;
    const short val = (ci < Cin) ? f2bf(wrow[(size_t)ci*9]) : (short)0;
    obase[(size_t)grp*73728 + kc*2048 + quad*128 + e] = val;
  }
}

// gw [256][512] fp32 -> gwT [512][256]
__global__ __launch_bounds__(256) void gwt_kernel(
    const float* __restrict__ gw, float* __restrict__ gwT)
{
  const int k = blockIdx.x, c = threadIdx.x;
  gwT[(size_t)k*256 + c] = gw[(size_t)c*512 + k];
}

// ---------------------------------------------------------------------------
// MFMA conv3x3, pad=1, 11x11. blockIdx.x = sample (possibly batched);
// block = 8 waves (512 thr), block tile 128co x 128px, wave tile 64co x 32px.
// A: fragment-ordered global bf16 (coalesced 1KB loads).
// B: staged per 128-ci group into LDS [px][ci] bf16 (stride 136, rows
//    121..127 zero sentinel) -- R5-verified synchronous staging.
// inA1 != nullptr selects pair-batched m-conv mode: samples 0..127 use inA,
// 128..255 use inA1, with per-pair tc/rpe extras.
// ---------------------------------------------------------------------------
__global__ __launch_bounds__(512) void conv_mfma_kernel(
    const float* __restrict__ inA, const float* __restrict__ inA1,
    const float* __restrict__ inB,
    int cinA, int Cin, int Cinp, int Cout,
    const short* __restrict__ wbf, const float* __restrict__ bias,
    float* __restrict__ out,
    int mMode, float4 tcs,
    const float* __restrict__ rp0, const float* __restrict__ rp1)
{
  __shared__ short Xs[128*136];
  const int samp = blockIdx.x;
  const int coB  = blockIdx.y * 128;
  const int t    = threadIdx.x;
  const int lane = t & 63;
  const int wv   = t >> 6;       // 0..7
  const int wy   = wv >> 2;      // co 64-half within block
  const int wx   = wv & 3;       // px 32-quarter within block
  const int l15  = lane & 15;
  const int quad = lane >> 4;
  const int G    = Cinp >> 7;

  const int pr = samp >> 7;      // pair select (only used when inA1 != null)
  const float* baseA = inA1 ? ((pr ? inA1 : inA) + (size_t)(samp & 127)*cinA*Nn)
                            : (inA + (size_t)samp*(size_t)cinA*Nn);
  const float* baseB = inB ? inB + (size_t)samp*(size_t)(Cin-cinA)*Nn : nullptr;
  const float mtc0 = pr ? tcs.z : tcs.x;
  const float mtc1 = pr ? tcs.w : tcs.y;
  const float* rp  = pr ? rp1 : rp0;

  int nout[2], py[2], pxx[2];
  #pragma unroll
  for (int ns = 0; ns < 2; ++ns){
    nout[ns] = wx*32 + ns*16 + l15;
    py[ns]  = nout[ns] / 11;
    pxx[ns] = nout[ns] % 11;
  }

  f32x4 acc[4][2];
  #pragma unroll
  for (int ms = 0; ms < 4; ++ms)
    #pragma unroll
    for (int ns = 0; ns < 2; ++ns) acc[ms][ns] = (f32x4){0.f,0.f,0.f,0.f};

  // per-wave weight base
  const short* wgbase = wbf + (size_t)(blockIdx.y*2 + wy)*G*73728 + lane*8;

  const int ngrp = (Cin + 127) >> 7;
  for (int grp = 0; grp < ngrp; ++grp){
    __syncthreads();
    // ---- stage 128 ci x 128 px into LDS as bf16 [px][ci] (R5 verbatim) ----
    for (int e = t; e < 128*128; e += 512){
      const int px = e & 127, cil = e >> 7;
      const int ci = grp*128 + cil;
      float v = 0.f;
      if (px < Nn && ci < Cin){
        if (mMode && ci >= 256)
          v = (ci == 256) ? mtc0 : (ci == 257) ? mtc1 : rp[px];
        else if (ci < cinA) v = baseA[(size_t)ci*Nn + px];
        else                v = baseB[(size_t)(ci-cinA)*Nn + px];
      }
      Xs[px*136 + cil] = f2bf(v);
    }
    __syncthreads();

    const int rem = Cin - grp*128;
    const short* wgrp = wgbase + (size_t)grp*73728;

    if (rem >= 128){
      for (int tap = 0; tap < 9; ++tap){
        const int dy = tap/3 - 1, dx = tap%3 - 1;
        int pp[2];
        #pragma unroll
        for (int ns = 0; ns < 2; ++ns){
          const int yy = py[ns] + dy, xx = pxx[ns] + dx;
          const bool ok = (nout[ns] < Nn) && yy >= 0 && yy < 11 && xx >= 0 && xx < 11;
          pp[ns] = ok ? yy*11 + xx : Nn;   // row 121 = zero sentinel
        }
        const short* wb = wgrp + tap*8192;
        #pragma unroll
        for (int kc = 0; kc < 4; ++kc){
          short8 a[4], b[2];
          #pragma unroll
          for (int ms = 0; ms < 4; ++ms)
            a[ms] = *(const short8*)(wb + kc*2048 + ms*512);
          #pragma unroll
          for (int ns = 0; ns < 2; ++ns)
            b[ns] = *(const short8*)(&Xs[pp[ns]*136 + kc*32 + quad*8]);
          #pragma unroll
          for (int ms = 0; ms < 4; ++ms)
            #pragma unroll
            for (int ns = 0; ns < 2; ++ns)
              acc[ms][ns] = __builtin_amdgcn_mfma_f32_16x16x32_bf16(
                                a[ms], b[ns], acc[ms][ns], 0, 0, 0);
        }
      }
    } else {
      const int nkc = (rem + 31) >> 5;
      for (int tap = 0; tap < 9; ++tap){
        const int dy = tap/3 - 1, dx = tap%3 - 1;
        int pp[2];
        #pragma unroll
        for (int ns = 0; ns < 2; ++ns){
          const int yy = py[ns] + dy, xx = pxx[ns] + dx;
          const bool ok = (nout[ns] < Nn) && yy >= 0 && yy < 11 && xx >= 0 && xx < 11;
          pp[ns] = ok ? yy*11 + xx : Nn;
        }
        const short* wb = wgrp + tap*8192;
        for (int kc = 0; kc < nkc; ++kc){
          short8 a[4], b[2];
          #pragma unroll
          for (int ms = 0; ms < 4; ++ms)
            a[ms] = *(const short8*)(wb + kc*2048 + ms*512);
          #pragma unroll
          for (int ns = 0; ns < 2; ++ns)
            b[ns] = *(const short8*)(&Xs[pp[ns]*136 + kc*32 + quad*8]);
          #pragma unroll
          for (int ms = 0; ms < 4; ++ms)
            #pragma unroll
            for (int ns = 0; ns < 2; ++ns)
              acc[ms][ns] = __builtin_amdgcn_mfma_f32_16x16x32_bf16(
                                a[ms], b[ns], acc[ms][ns], 0, 0, 0);
        }
      }
    }
  }

  // ---- epilogue: C layout col=lane&15 (n), row=quad*4+r (m) ----
  #pragma unroll
  for (int ms = 0; ms < 4; ++ms)
    #pragma unroll
    for (int ns = 0; ns < 2; ++ns){
      const int n = nout[ns];
      if (n < Nn){
        const int mbase = coB + wy*64 + ms*16 + quad*4;
        #pragma unroll
        for (int r = 0; r < 4; ++r)
          out[((size_t)samp*Cout + mbase + r)*Nn + n] = acc[ms][ns][r] + bias[mbase + r];
      }
    }
}

// ---------------------------------------------------------------------------
// LayerNorm over (C,H,W) per sample. out = alpha*maybe_relu(LN(x)*g+b)+addend
// ---------------------------------------------------------------------------
__global__ __launch_bounds__(256) void ln_kernel(
    const float* __restrict__ x, const float* __restrict__ g, const float* __restrict__ bb,
    float* __restrict__ out, const float* __restrict__ alpha,
    const float* __restrict__ addend, int relu)
{
  const size_t base = (size_t)blockIdx.x * CHWn;
  const f32x4* xs = (const f32x4*)(x + base);
  const int NV = CHWn/4;   // 7744
  float sum = 0.f, ss = 0.f;
  for (int i = threadIdx.x; i < NV; i += 256){
    f32x4 v = xs[i];
    sum += v.x + v.y + v.z + v.w;
    ss  += v.x*v.x + v.y*v.y + v.z*v.z + v.w*v.w;
  }
  #pragma unroll
  for (int o = 32; o > 0; o >>= 1){ sum += __shfl_down(sum, o, 64); ss += __shfl_down(ss, o, 64); }
  __shared__ float r1[4], r2[4];
  const int wid = threadIdx.x >> 6;
  if ((threadIdx.x & 63) == 0){ r1[wid] = sum; r2[wid] = ss; }
  __syncthreads();
  sum = r1[0]+r1[1]+r1[2]+r1[3];
  ss  = r2[0]+r2[1]+r2[2]+r2[3];
  const float mean = sum * (1.f/CHWn);
  const float var  = ss * (1.f/CHWn) - mean*mean;
  const float inv  = rsqrtf(var + EPSf);
  const float a = alpha ? *alpha : 1.f;
  const f32x4* gv = (const f32x4*)g;
  const f32x4* bv = (const f32x4*)bb;
  const f32x4* av = addend ? (const f32x4*)(addend + base) : nullptr;
  f32x4* ov = (f32x4*)(out + base);
  for (int i = threadIdx.x; i < NV; i += 256){
    f32x4 v = (xs[i] - mean) * inv * gv[i] + bv[i];
    if (relu){ v.x=fmaxf(v.x,0.f); v.y=fmaxf(v.y,0.f); v.z=fmaxf(v.z,0.f); v.w=fmaxf(v.w,0.f); }
    v *= a;
    if (av) v += av[i];
    ov[i] = v;
  }
}

// ---------------------------------------------------------------------------
// Fused attention per (sample, head); qm masks the q-sample index so a
// shared-q buffer can serve pair-batched kv (inter mode).
// ---------------------------------------------------------------------------
template<int HDt, int CPT, int NPASS>
__global__ __launch_bounds__(256) void attn_kernel(
    const float* __restrict__ q, const float* __restrict__ k, const float* __restrict__ v,
    float* __restrict__ o, int qs, int ks, int os, int qm)
{
  __shared__ float T[Nn*132];
  const int nh_ = Cn / HDt;
  const int samp = blockIdx.x / nh_;
  const int hh = blockIdx.x % nh_;
  const size_t qoff  = ((size_t)(samp & qm)*qs + hh*HDt)*Nn;
  const size_t kvoff = ((size_t)samp*ks + hh*HDt)*Nn;
  const size_t ooff  = ((size_t)samp*os + hh*HDt)*Nn;
  const int t = threadIdx.x;
  {
    const int tn = t >> 4, tm = t & 15;
    const int n0 = tn*8, m0 = tm*8;
    float acc[8][8];
    #pragma unroll
    for (int a2=0;a2<8;a2++)
      #pragma unroll
      for (int b2=0;b2<8;b2++) acc[a2][b2] = 0.f;
    const float* qp = q + qoff + n0;
    const float* kp = k + kvoff + m0;
    #pragma unroll 2
    for (int d=0; d<HDt; ++d){
      float qv[8], kv[8];
      #pragma unroll
      for (int j2=0;j2<8;j2++){ qv[j2] = qp[d*Nn + j2]; kv[j2] = kp[d*Nn + j2]; }
      #pragma unroll
      for (int a2=0;a2<8;a2++)
        #pragma unroll
        for (int b2=0;b2<8;b2++) acc[a2][b2] = fmaf(qv[a2], kv[b2], acc[a2][b2]);
    }
    #pragma unroll
    for (int b2=0;b2<8;b2++){
      const int m = m0 + b2;
      if (m < Nn){
        #pragma unroll
        for (int a2=0;a2<8;a2++) T[m*132 + n0 + a2] = acc[a2][b2] * SCALEf;
      }
    }
  }
  __syncthreads();
  if (t < Nn){
    float mx = -1e30f;
    for (int m2=0;m2<Nn;m2++) mx = fmaxf(mx, T[m2*132+t]);
    float sum = 0.f;
    for (int m2=0;m2<Nn;m2++){ float e = __expf(T[m2*132+t]-mx); sum += e; T[m2*132+t] = e; }
    const float invs = 1.f/sum;
    for (int m2=0;m2<Nn;m2++) T[m2*132+t] *= invs;
  }
  __syncthreads();
  {
    const int ng_ = t & 15, cg = t >> 4;
    const int an0 = ng_*8;
    for (int pass=0; pass<NPASS; ++pass){
      const int c0 = pass*64 + cg*CPT;
      float av[CPT][8];
      #pragma unroll
      for (int ci2=0;ci2<CPT;ci2++)
        #pragma unroll
        for (int j2=0;j2<8;j2++) av[ci2][j2] = 0.f;
      for (int m2=0;m2<Nn;m2++){
        float tv[8];
        #pragma unroll
        for (int j2=0;j2<8;j2++) tv[j2] = T[m2*132 + an0 + j2];
        #pragma unroll
        for (int ci2=0;ci2<CPT;ci2++){
          const float vv = v[kvoff + (size_t)(c0+ci2)*Nn + m2];
          #pragma unroll
          for (int j2=0;j2<8;j2++) av[ci2][j2] = fmaf(vv, tv[j2], av[ci2][j2]);
        }
      }
      #pragma unroll
      for (int ci2=0;ci2<CPT;ci2++){
        float* op = o + ooff + (size_t)(c0+ci2)*Nn + an0;
        #pragma unroll
        for (int j2=0;j2<8;j2++) if (an0+j2 < Nn) op[j2] = av[ci2][j2];
      }
    }
  }
}

// Spatial mean per (sample, channel). grid=(samples,32).
__global__ __launch_bounds__(128) void mean_kernel(const float* __restrict__ x, float* __restrict__ out)
{
  const int s = blockIdx.x; const int c0 = blockIdx.y*8;
  __shared__ float r[2];
  for (int cc=0; cc<8; ++cc){
    const int c = c0+cc;
    float v = 0.f;
    if (threadIdx.x < Nn) v = x[((size_t)s*Cn + c)*Nn + threadIdx.x];
    #pragma unroll
    for (int o=32;o>0;o>>=1) v += __shfl_down(v, o, 64);
    if ((threadIdx.x & 63) == 0) r[threadIdx.x>>6] = v;
    __syncthreads();
    if (threadIdx.x == 0) out[(size_t)s*Cn + c] = (r[0]+r[1]) * (1.f/Nn);
    __syncthreads();
  }
}

// gate[b,c] = sigmoid( gwT[:,c] . [meanX(b&xm); meanM(b)] + gb[c] )
__global__ __launch_bounds__(256) void gate_kernel(
    const float* __restrict__ meanX, const float* __restrict__ meanM,
    const float* __restrict__ gwT, const float* __restrict__ gb,
    float* __restrict__ gate, int xm)
{
  const int b = blockIdx.x;
  __shared__ float mv[512];
  mv[threadIdx.x]     = meanX[(size_t)(b & xm)*Cn + threadIdx.x];
  mv[256+threadIdx.x] = meanM[(size_t)b*Cn + threadIdx.x];
  __syncthreads();
  float acc = gb[threadIdx.x];
  for (int k2=0;k2<512;k2++) acc = fmaf(gwT[(size_t)k2*256 + threadIdx.x], mv[k2], acc);
  gate[(size_t)b*Cn + threadIdx.x] = 1.f/(1.f+__expf(-acc));
}

// out (+)= msg * gate
__global__ __launch_bounds__(256) void accum_kernel(
    const float* __restrict__ msg, const float* __restrict__ gate,
    float* __restrict__ outs, int init)
{
  const size_t idx = (size_t)blockIdx.x*256 + threadIdx.x;
  if (idx >= SLICEsz) return;
  const size_t t_ = idx / Nn;
  const int c = (int)(t_ & 255);
  const int b = (int)(t_ >> 8);
  const float v = msg[idx] * gate[(size_t)b*Cn + c];
  outs[idx] = init ? v : (outs[idx] + v);
}

// hi = iia*hi + (1-iia)*outi
__global__ __launch_bounds__(256) void comb_kernel(float* __restrict__ hi,
    const float* __restrict__ outi, const float* __restrict__ iia)
{
  const size_t idx = (size_t)blockIdx.x*256 + threadIdx.x;
  if (idx >= SLICEsz) return;
  const float a = *iia;
  hi[idx] = a*hi[idx] + (1.f-a)*outi[idx];
}

// rh = sigmoid(zrq[:,256:512]) * h   (batched: nelem = cn*SLICEsz)
__global__ __launch_bounds__(256) void rh_kernel(const float* __restrict__ zrq,
    const float* __restrict__ h, float* __restrict__ rh, size_t nelem)
{
  const size_t idx = (size_t)blockIdx.x*256 + threadIdx.x;
  if (idx >= nelem) return;
  const int n_ = (int)(idx % Nn);
  const size_t t_ = idx / Nn;
  const int c = (int)(t_ & 255);
  const size_t s = t_ >> 8;
  float r = zrq[(s*512 + 256 + c)*Nn + n_];
  r = 1.f/(1.f+__expf(-r));
  rh[idx] = r*h[idx];
}

// nh = (1-z)*h + z*tanh(hq) + h   (batched)
__global__ __launch_bounds__(256) void nh_kernel(const float* __restrict__ zrq,
    const float* __restrict__ hq, const float* __restrict__ h,
    float* __restrict__ nh, size_t nelem)
{
  const size_t idx = (size_t)blockIdx.x*256 + threadIdx.x;
  if (idx >= nelem) return;
  const int n_ = (int)(idx % Nn);
  const size_t t_ = idx / Nn;
  const int c = (int)(t_ & 255);
  const size_t s = t_ >> 8;
  float z = zrq[(s*512 + c)*Nn + n_];
  z = 1.f/(1.f+__expf(-z));
  const float hv = h[idx];
  nh[idx] = (1.f-z)*hv + z*tanhf(hq[idx]) + hv;
}

// ---------------------------------------------------------------------------
// Host orchestration
// ---------------------------------------------------------------------------
static const int PJ[5][4] = {{1,2,0,0},{0,2,3,0},{0,1,3,4},{1,2,4,0},{2,3,0,0}};
static const int PNP[5]   = {2,3,4,3,2};

extern "C" void kernel_launch(void* const* d_in, const int* in_sizes, int n_in,
                              void* d_out, int out_size, void* d_ws, size_t ws_size,
                              hipStream_t stream)
{
  (void)in_sizes; (void)n_in; (void)out_size;
  const float* x   = (const float*)d_in[0];
  const float* ing = (const float*)d_in[1];
  const float* inb = (const float*)d_in[2];
  const float* iqw = (const float*)d_in[3];
  const float* iqb = (const float*)d_in[4];
  const float* ikw = (const float*)d_in[5];
  const float* ikb = (const float*)d_in[6];
  const float* ivw = (const float*)d_in[7];
  const float* ivb = (const float*)d_in[8];
  const float* iow = (const float*)d_in[9];
  const float* iob = (const float*)d_in[10];
  const float* iong= (const float*)d_in[11];
  const float* ionb= (const float*)d_in[12];
  const float* ia  = (const float*)d_in[13];
  const float* eng = (const float*)d_in[14];
  const float* enb = (const float*)d_in[15];
  const float* rpe = (const float*)d_in[16];
  const float* mw  = (const float*)d_in[17];
  const float* mb  = (const float*)d_in[18];
  const float* eqw = (const float*)d_in[19];
  const float* eqb = (const float*)d_in[20];
  const float* ekw = (const float*)d_in[21];
  const float* ekb = (const float*)d_in[22];
  const float* evw = (const float*)d_in[23];
  const float* evb = (const float*)d_in[24];
  const float* gw  = (const float*)d_in[25];
  const float* gb  = (const float*)d_in[26];
  const float* eow = (const float*)d_in[27];
  const float* eob = (const float*)d_in[28];
  const float* eong= (const float*)d_in[29];
  const float* eonb= (const float*)d_in[30];
  const float* iia = (const float*)d_in[31];
  const float* zrw = (const float*)d_in[32];
  const float* zrb = (const float*)d_in[33];
  const float* hww = (const float*)d_in[34];
  const float* hwb = (const float*)d_in[35];
  const float* ng  = (const float*)d_in[36];
  const float* nbg = (const float*)d_in[37];

  // ---- workspace layout (floats) ----
  float* W = (float*)d_ws;
  size_t off = 0;
  float* h      = W + off; off += FULLsz + 1024;          // persistent state
  float* big    = W + off; off += 6*SLICEsz + 1024;       // qkv / y+kv / zrq
  float* p2     = W + off; off += 2*SLICEsz + 1024;       // attn out / msg / hq
  float* xsl    = W + off; off += 2*SLICEsz + 1024;       // xn / rh / nh
  float* qsl    = W + off; off += SLA;                    // eq
  float* osl    = W + off; off += SLA;                    // inter accumulation
  float* meanXb = W + off; off += Bn*Cn;
  float* meanM  = W + off; off += 2*Bn*Cn;                // pair-batched
  float* gateb  = W + off; off += 2*Bn*Cn;
  float* bqkv   = W + off; off += 768;                    // concat bias q|k|v
  float* bekv   = W + off; off += 512;                    // concat bias ek|ev
  float* gwT    = W + off; off += 512*256;                // transposed gate weight
  // bf16 weight buffers (shorts), allocated on float boundary
  short* WB = (short*)(W + off);
  size_t so = 0;
  short* iqB = WB + so; so += (size_t)256*9*256;          // iq|ik|iv contiguous
  short* ikB = WB + so; so += (size_t)256*9*256;
  short* ivB = WB + so; so += (size_t)256*9*256;
  short* ioB = WB + so; so += (size_t)256*9*256;
  short* eqB = WB + so; so += (size_t)256*9*256;
  short* ekB = WB + so; so += (size_t)256*9*256;          // ek|ev contiguous
  short* evB = WB + so; so += (size_t)256*9*256;
  short* eoB = WB + so; so += (size_t)256*9*256;
  short* mB_ = WB + so; so += (size_t)256*9*384;
  short* zrB = WB + so; so += (size_t)512*9*512;
  short* hwB = WB + so; so += (size_t)256*9*512;
  off += (so + 1) / 2;
  if (ws_size < off * sizeof(float)) return;              // diagnostic guard

  float* hi = (float*)d_out;                              // full arena: intra out / comb

  hipMemcpyAsync(h, x, FULLsz*sizeof(float), hipMemcpyDeviceToDevice, stream);
  hipMemcpyAsync(bqkv,     iqb, 256*sizeof(float), hipMemcpyDeviceToDevice, stream);
  hipMemcpyAsync(bqkv+256, ikb, 256*sizeof(float), hipMemcpyDeviceToDevice, stream);
  hipMemcpyAsync(bqkv+512, ivb, 256*sizeof(float), hipMemcpyDeviceToDevice, stream);
  hipMemcpyAsync(bekv,     ekb, 256*sizeof(float), hipMemcpyDeviceToDevice, stream);
  hipMemcpyAsync(bekv+256, evb, 256*sizeof(float), hipMemcpyDeviceToDevice, stream);

  // ---- weight prep (once per call) ----
  wprep_kernel<<<dim3(256,9),128,0,stream>>>(iqw, iqB, 256, 256);
  wprep_kernel<<<dim3(256,9),128,0,stream>>>(ikw, ikB, 256, 256);
  wprep_kernel<<<dim3(256,9),128,0,stream>>>(ivw, ivB, 256, 256);
  wprep_kernel<<<dim3(256,9),128,0,stream>>>(iow, ioB, 256, 256);
  wprep_kernel<<<dim3(256,9),128,0,stream>>>(eqw, eqB, 256, 256);
  wprep_kernel<<<dim3(256,9),128,0,stream>>>(ekw, ekB, 256, 256);
  wprep_kernel<<<dim3(256,9),128,0,stream>>>(evw, evB, 256, 256);
  wprep_kernel<<<dim3(256,9),128,0,stream>>>(eow, eoB, 256, 256);
  wprep_kernel<<<dim3(256,9),128,0,stream>>>(mw,  mB_, 259, 384);
  wprep_kernel<<<dim3(512,9),128,0,stream>>>(zrw, zrB, 512, 512);
  wprep_kernel<<<dim3(256,9),128,0,stream>>>(hww, hwB, 512, 512);
  gwt_kernel<<<512,256,0,stream>>>(gw, gwT);

  const int gridSlc = (int)(SLICEsz / 256);   // 15,488 exact
  const float4 f4z = {0.f,0.f,0.f,0.f};

  // regular conv: NS_ = sample-batch multiplier (contiguous inputs/outputs)
  #define CONV(inA_, inB_, Cin_, Cinp_, Cout_, wb_, bi_, out_, NS_)              \
    conv_mfma_kernel<<<dim3(Bn*(NS_), (Cout_)/128), 512, 0, stream>>>(           \
        inA_, nullptr, inB_, 256, Cin_, Cinp_, Cout_, wb_, bi_, out_,            \
        0, f4z, nullptr, nullptr)

  for (int it = 0; it < NITERn; ++it){
    // ---------------- intra_all (per slice) ----------------
    for (int s = 0; s < Sn; ++s){
      const float* hs = h + (size_t)s*SLICEsz;
      ln_kernel<<<Bn,256,0,stream>>>(hs, ing, inb, xsl, nullptr, nullptr, 0);
      CONV(xsl, nullptr, 256, 256, 768, iqB, bqkv, big, 1);                      // q|k|v
      attn_kernel<256,4,4><<<Bn,256,0,stream>>>(big, big + (size_t)256*Nn,
                                                big + (size_t)512*Nn, p2,
                                                768, 768, 256, 0x7fffffff);
      CONV(p2, nullptr, 256, 256, 256, ioB, iob, big, 1);                        // io-out
      ln_kernel<<<Bn,256,0,stream>>>(big, iong, ionb, hi + (size_t)s*SLICEsz, ia, xsl, 1);
    }

    // ---------------- inter (per i, pair-chunks of 2) ----------------
    for (int i = 0; i < Sn; ++i){
      ln_kernel<<<Bn,256,0,stream>>>(h + (size_t)i*SLICEsz, eng, enb, xsl, nullptr, nullptr, 0);
      CONV(xsl, nullptr, 256, 256, 256, eqB, eqb, qsl, 1);
      mean_kernel<<<dim3(Bn,32),128,0,stream>>>(xsl, meanXb);
      const int np = PNP[i];
      int done = 0; int first = 1;
      while (done < np){
        const int cn = (np - done >= 2) ? 2 : 1;
        const int j0 = PJ[i][done];
        const int j1 = PJ[i][done + cn - 1];
        const float4 tcs = { (i < j0) ? 1.f : -1.f, fabsf((float)(i - j0)) * 0.5f,
                             (i < j1) ? 1.f : -1.f, fabsf((float)(i - j1)) * 0.5f };
        const int r0 = (((i - j0 + 1) % 4) + 4) % 4;
        const int r1 = (((i - j1 + 1) % 4) + 4) % 4;
        // y (pair-batched m-conv) -> big[0 : cn*S)
        conv_mfma_kernel<<<dim3(Bn*cn,2),512,0,stream>>>(
            h + (size_t)j0*SLICEsz, h + (size_t)j1*SLICEsz, nullptr,
            256, 259, 384, 256, mB_, mb, big,
            1, tcs, rpe + (size_t)r0*Nn, rpe + (size_t)r1*Nn);
        // k|v -> big[2S : 2S+2cn*S)
        CONV(big, nullptr, 256, 256, 512, ekB, bekv, big + 2*SLICEsz, cn);
        // msg_raw -> big[0 : cn*S)  (y dead)
        attn_kernel<32,2,1><<<Bn*cn*HEADSn,256,0,stream>>>(
            qsl, big + 2*SLICEsz, big + 2*SLICEsz + (size_t)256*Nn, big,
            256, 512, 256, 127);
        // eo -> p2 ; LN(relu) in place
        CONV(big, nullptr, 256, 256, 256, eoB, eob, p2, cn);
        ln_kernel<<<Bn*cn,256,0,stream>>>(p2, eong, eonb, p2, nullptr, nullptr, 1);
        mean_kernel<<<dim3(Bn*cn,32),128,0,stream>>>(p2, meanM);
        gate_kernel<<<Bn*cn,256,0,stream>>>(meanXb, meanM, gwT, gb, gateb, 127);
        accum_kernel<<<gridSlc,256,0,stream>>>(p2, gateb, osl, first);
        if (cn == 2)
          accum_kernel<<<gridSlc,256,0,stream>>>(p2 + SLICEsz, gateb + Bn*Cn, osl, 0);
        first = 0; done += cn;
      }
      comb_kernel<<<gridSlc,256,0,stream>>>(hi + (size_t)i*SLICEsz, osl, iia);   // hi=comb
    }

    // ---------------- GRU + final LN (slice-pairs) ----------------
    for (int s0 = 0; s0 < Sn; s0 += 2){
      const int cn = (Sn - s0 >= 2) ? 2 : 1;
      const float* hs = h + (size_t)s0*SLICEsz;
      float* cs = hi + (size_t)s0*SLICEsz;   // comb
      CONV(cs, hs, 512, 512, 512, zrB, zrb, big, cn);                            // zrq
      rh_kernel<<<gridSlc*cn,256,0,stream>>>(big, hs, xsl, (size_t)cn*SLICEsz);  // xsl = r*h
      CONV(cs, xsl, 512, 512, 256, hwB, hwb, p2, cn);                            // hq
      nh_kernel<<<gridSlc*cn,256,0,stream>>>(big, p2, hs, xsl, (size_t)cn*SLICEsz);
      float* dst = (it == NITERn-1) ? cs : (float*)hs;
      ln_kernel<<<Bn*cn,256,0,stream>>>(xsl, ng, nbg, dst, nullptr, nullptr, 0);
    }
  }
  #undef CONV
}

// Round 6
// 14250.298 us; speedup vs baseline: 2.3619x; 1.0774x over previous
//
#include <hip/hip_runtime.h>
#include <cstdint>
#include <cstddef>
#include <cmath>

// ---------------------------------------------------------------------------
// LiveSAL round 8: R7 (verified 15.35ms) + intra section batched in
// slice-pairs (same pattern as the verified GRU/inter batching):
//   ln 256 blks, qkv (256,6), attn 256, io (256,2), ln2 256.
// Conv staging stays the R5-verified synchronous path. No new device code.
// ---------------------------------------------------------------------------

#define Sn 5
#define Bn 128
#define Cn 256
#define Nn 121          // 11*11
#define HEADSn 8
#define NITERn 2
#define EPSf 1e-5f
#define SCALEf 0.0625f  // 256^-0.5
#define CHWn (Cn*Nn)    // 30976

static const size_t SLICEsz = (size_t)Bn*CHWn;       // 3,964,928 floats
static const size_t FULLsz  = (size_t)Sn*SLICEsz;    // 19,824,640 floats
static const size_t SLA     = SLICEsz + 1024;        // padded slice arena

typedef __attribute__((ext_vector_type(8))) short short8;
typedef __attribute__((ext_vector_type(4))) float f32x4;

static __device__ __forceinline__ short f2bf(float f){
  union { float f; unsigned u; } x; x.f = f;
  unsigned r = (x.u + 0x7FFFu + ((x.u >> 16) & 1u)) >> 16;   // RNE
  return (short)r;
}

// ---------------------------------------------------------------------------
// Weight prep: fp32 [Cout][Cin][3][3] -> bf16 fragment-ordered
//   AW[coH][grp][tap][kc][ms][lane][8],  lane = quad*16+l15
// where co = coH*64 + ms*16 + l15, ci = grp*128 + kc*32 + quad*8 + e.
// Strides (shorts): grp=73728 (=9*8192), tap=8192, kc=2048, ms=512.
// ---------------------------------------------------------------------------
__global__ __launch_bounds__(128) void wprep_kernel(
    const float* __restrict__ w, short* __restrict__ o, int Cin, int Cinp)
{
  const int co = blockIdx.x, tap = blockIdx.y;
  const int G = Cinp >> 7;
  const int coH = co >> 6, ms = (co >> 4) & 3, l15 = co & 15;
  const float* wrow = w + (size_t)co*Cin*9 + tap;
  short* obase = o + (size_t)coH*G*73728 + (size_t)tap*8192 + ms*512 + l15*8;
  for (int ci = threadIdx.x; ci < Cinp; ci += 128){
    const int grp = ci >> 7, kc = (ci >> 5) & 3, quad = (ci >> 3) & 3, e = ci & 7;
    const short val = (ci < Cin) ? f2bf(wrow[(size_t)ci*9]) : (short)0;
    obase[(size_t)grp*73728 + kc*2048 + quad*128 + e] = val;
  }
}

// gw [256][512] fp32 -> gwT [512][256]
__global__ __launch_bounds__(256) void gwt_kernel(
    const float* __restrict__ gw, float* __restrict__ gwT)
{
  const int k = blockIdx.x, c = threadIdx.x;
  gwT[(size_t)k*256 + c] = gw[(size_t)c*512 + k];
}

// ---------------------------------------------------------------------------
// MFMA conv3x3, pad=1, 11x11. blockIdx.x = sample (possibly batched);
// block = 8 waves (512 thr), block tile 128co x 128px, wave tile 64co x 32px.
// A: fragment-ordered global bf16 (coalesced 1KB loads).
// B: staged per 128-ci group into LDS [px][ci] bf16 (stride 136, rows
//    121..127 zero sentinel) -- R5-verified synchronous staging.
// inA1 != nullptr selects pair-batched m-conv mode: samples 0..127 use inA,
// 128..255 use inA1, with per-pair tc/rpe extras.
// ---------------------------------------------------------------------------
__global__ __launch_bounds__(512) void conv_mfma_kernel(
    const float* __restrict__ inA, const float* __restrict__ inA1,
    const float* __restrict__ inB,
    int cinA, int Cin, int Cinp, int Cout,
    const short* __restrict__ wbf, const float* __restrict__ bias,
    float* __restrict__ out,
    int mMode, float4 tcs,
    const float* __restrict__ rp0, const float* __restrict__ rp1)
{
  __shared__ short Xs[128*136];
  const int samp = blockIdx.x;
  const int coB  = blockIdx.y * 128;
  const int t    = threadIdx.x;
  const int lane = t & 63;
  const int wv   = t >> 6;       // 0..7
  const int wy   = wv >> 2;      // co 64-half within block
  const int wx   = wv & 3;       // px 32-quarter within block
  const int l15  = lane & 15;
  const int quad = lane >> 4;
  const int G    = Cinp >> 7;

  const int pr = samp >> 7;      // pair select (only used when inA1 != null)
  const float* baseA = inA1 ? ((pr ? inA1 : inA) + (size_t)(samp & 127)*cinA*Nn)
                            : (inA + (size_t)samp*(size_t)cinA*Nn);
  const float* baseB = inB ? inB + (size_t)samp*(size_t)(Cin-cinA)*Nn : nullptr;
  const float mtc0 = pr ? tcs.z : tcs.x;
  const float mtc1 = pr ? tcs.w : tcs.y;
  const float* rp  = pr ? rp1 : rp0;

  int nout[2], py[2], pxx[2];
  #pragma unroll
  for (int ns = 0; ns < 2; ++ns){
    nout[ns] = wx*32 + ns*16 + l15;
    py[ns]  = nout[ns] / 11;
    pxx[ns] = nout[ns] % 11;
  }

  f32x4 acc[4][2];
  #pragma unroll
  for (int ms = 0; ms < 4; ++ms)
    #pragma unroll
    for (int ns = 0; ns < 2; ++ns) acc[ms][ns] = (f32x4){0.f,0.f,0.f,0.f};

  // per-wave weight base
  const short* wgbase = wbf + (size_t)(blockIdx.y*2 + wy)*G*73728 + lane*8;

  const int ngrp = (Cin + 127) >> 7;
  for (int grp = 0; grp < ngrp; ++grp){
    __syncthreads();
    // ---- stage 128 ci x 128 px into LDS as bf16 [px][ci] (R5 verbatim) ----
    for (int e = t; e < 128*128; e += 512){
      const int px = e & 127, cil = e >> 7;
      const int ci = grp*128 + cil;
      float v = 0.f;
      if (px < Nn && ci < Cin){
        if (mMode && ci >= 256)
          v = (ci == 256) ? mtc0 : (ci == 257) ? mtc1 : rp[px];
        else if (ci < cinA) v = baseA[(size_t)ci*Nn + px];
        else                v = baseB[(size_t)(ci-cinA)*Nn + px];
      }
      Xs[px*136 + cil] = f2bf(v);
    }
    __syncthreads();

    const int rem = Cin - grp*128;
    const short* wgrp = wgbase + (size_t)grp*73728;

    if (rem >= 128){
      for (int tap = 0; tap < 9; ++tap){
        const int dy = tap/3 - 1, dx = tap%3 - 1;
        int pp[2];
        #pragma unroll
        for (int ns = 0; ns < 2; ++ns){
          const int yy = py[ns] + dy, xx = pxx[ns] + dx;
          const bool ok = (nout[ns] < Nn) && yy >= 0 && yy < 11 && xx >= 0 && xx < 11;
          pp[ns] = ok ? yy*11 + xx : Nn;   // row 121 = zero sentinel
        }
        const short* wb = wgrp + tap*8192;
        #pragma unroll
        for (int kc = 0; kc < 4; ++kc){
          short8 a[4], b[2];
          #pragma unroll
          for (int ms = 0; ms < 4; ++ms)
            a[ms] = *(const short8*)(wb + kc*2048 + ms*512);
          #pragma unroll
          for (int ns = 0; ns < 2; ++ns)
            b[ns] = *(const short8*)(&Xs[pp[ns]*136 + kc*32 + quad*8]);
          #pragma unroll
          for (int ms = 0; ms < 4; ++ms)
            #pragma unroll
            for (int ns = 0; ns < 2; ++ns)
              acc[ms][ns] = __builtin_amdgcn_mfma_f32_16x16x32_bf16(
                                a[ms], b[ns], acc[ms][ns], 0, 0, 0);
        }
      }
    } else {
      const int nkc = (rem + 31) >> 5;
      for (int tap = 0; tap < 9; ++tap){
        const int dy = tap/3 - 1, dx = tap%3 - 1;
        int pp[2];
        #pragma unroll
        for (int ns = 0; ns < 2; ++ns){
          const int yy = py[ns] + dy, xx = pxx[ns] + dx;
          const bool ok = (nout[ns] < Nn) && yy >= 0 && yy < 11 && xx >= 0 && xx < 11;
          pp[ns] = ok ? yy*11 + xx : Nn;
        }
        const short* wb = wgrp + tap*8192;
        for (int kc = 0; kc < nkc; ++kc){
          short8 a[4], b[2];
          #pragma unroll
          for (int ms = 0; ms < 4; ++ms)
            a[ms] = *(const short8*)(wb + kc*2048 + ms*512);
          #pragma unroll
          for (int ns = 0; ns < 2; ++ns)
            b[ns] = *(const short8*)(&Xs[pp[ns]*136 + kc*32 + quad*8]);
          #pragma unroll
          for (int ms = 0; ms < 4; ++ms)
            #pragma unroll
            for (int ns = 0; ns < 2; ++ns)
              acc[ms][ns] = __builtin_amdgcn_mfma_f32_16x16x32_bf16(
                                a[ms], b[ns], acc[ms][ns], 0, 0, 0);
        }
      }
    }
  }

  // ---- epilogue: C layout col=lane&15 (n), row=quad*4+r (m) ----
  #pragma unroll
  for (int ms = 0; ms < 4; ++ms)
    #pragma unroll
    for (int ns = 0; ns < 2; ++ns){
      const int n = nout[ns];
      if (n < Nn){
        const int mbase = coB + wy*64 + ms*16 + quad*4;
        #pragma unroll
        for (int r = 0; r < 4; ++r)
          out[((size_t)samp*Cout + mbase + r)*Nn + n] = acc[ms][ns][r] + bias[mbase + r];
      }
    }
}

// ---------------------------------------------------------------------------
// LayerNorm over (C,H,W) per sample. out = alpha*maybe_relu(LN(x)*g+b)+addend
// ---------------------------------------------------------------------------
__global__ __launch_bounds__(256) void ln_kernel(
    const float* __restrict__ x, const float* __restrict__ g, const float* __restrict__ bb,
    float* __restrict__ out, const float* __restrict__ alpha,
    const float* __restrict__ addend, int relu)
{
  const size_t base = (size_t)blockIdx.x * CHWn;
  const f32x4* xs = (const f32x4*)(x + base);
  const int NV = CHWn/4;   // 7744
  float sum = 0.f, ss = 0.f;
  for (int i = threadIdx.x; i < NV; i += 256){
    f32x4 v = xs[i];
    sum += v.x + v.y + v.z + v.w;
    ss  += v.x*v.x + v.y*v.y + v.z*v.z + v.w*v.w;
  }
  #pragma unroll
  for (int o = 32; o > 0; o >>= 1){ sum += __shfl_down(sum, o, 64); ss += __shfl_down(ss, o, 64); }
  __shared__ float r1[4], r2[4];
  const int wid = threadIdx.x >> 6;
  if ((threadIdx.x & 63) == 0){ r1[wid] = sum; r2[wid] = ss; }
  __syncthreads();
  sum = r1[0]+r1[1]+r1[2]+r1[3];
  ss  = r2[0]+r2[1]+r2[2]+r2[3];
  const float mean = sum * (1.f/CHWn);
  const float var  = ss * (1.f/CHWn) - mean*mean;
  const float inv  = rsqrtf(var + EPSf);
  const float a = alpha ? *alpha : 1.f;
  const f32x4* gv = (const f32x4*)g;
  const f32x4* bv = (const f32x4*)bb;
  const f32x4* av = addend ? (const f32x4*)(addend + base) : nullptr;
  f32x4* ov = (f32x4*)(out + base);
  for (int i = threadIdx.x; i < NV; i += 256){
    f32x4 v = (xs[i] - mean) * inv * gv[i] + bv[i];
    if (relu){ v.x=fmaxf(v.x,0.f); v.y=fmaxf(v.y,0.f); v.z=fmaxf(v.z,0.f); v.w=fmaxf(v.w,0.f); }
    v *= a;
    if (av) v += av[i];
    ov[i] = v;
  }
}

// ---------------------------------------------------------------------------
// Fused attention per (sample, head); qm masks the q-sample index so a
// shared-q buffer can serve pair-batched kv (inter mode).
// ---------------------------------------------------------------------------
template<int HDt, int CPT, int NPASS>
__global__ __launch_bounds__(256) void attn_kernel(
    const float* __restrict__ q, const float* __restrict__ k, const float* __restrict__ v,
    float* __restrict__ o, int qs, int ks, int os, int qm)
{
  __shared__ float T[Nn*132];
  const int nh_ = Cn / HDt;
  const int samp = blockIdx.x / nh_;
  const int hh = blockIdx.x % nh_;
  const size_t qoff  = ((size_t)(samp & qm)*qs + hh*HDt)*Nn;
  const size_t kvoff = ((size_t)samp*ks + hh*HDt)*Nn;
  const size_t ooff  = ((size_t)samp*os + hh*HDt)*Nn;
  const int t = threadIdx.x;
  {
    const int tn = t >> 4, tm = t & 15;
    const int n0 = tn*8, m0 = tm*8;
    float acc[8][8];
    #pragma unroll
    for (int a2=0;a2<8;a2++)
      #pragma unroll
      for (int b2=0;b2<8;b2++) acc[a2][b2] = 0.f;
    const float* qp = q + qoff + n0;
    const float* kp = k + kvoff + m0;
    #pragma unroll 2
    for (int d=0; d<HDt; ++d){
      float qv[8], kv[8];
      #pragma unroll
      for (int j2=0;j2<8;j2++){ qv[j2] = qp[d*Nn + j2]; kv[j2] = kp[d*Nn + j2]; }
      #pragma unroll
      for (int a2=0;a2<8;a2++)
        #pragma unroll
        for (int b2=0;b2<8;b2++) acc[a2][b2] = fmaf(qv[a2], kv[b2], acc[a2][b2]);
    }
    #pragma unroll
    for (int b2=0;b2<8;b2++){
      const int m = m0 + b2;
      if (m < Nn){
        #pragma unroll
        for (int a2=0;a2<8;a2++) T[m*132 + n0 + a2] = acc[a2][b2] * SCALEf;
      }
    }
  }
  __syncthreads();
  if (t < Nn){
    float mx = -1e30f;
    for (int m2=0;m2<Nn;m2++) mx = fmaxf(mx, T[m2*132+t]);
    float sum = 0.f;
    for (int m2=0;m2<Nn;m2++){ float e = __expf(T[m2*132+t]-mx); sum += e; T[m2*132+t] = e; }
    const float invs = 1.f/sum;
    for (int m2=0;m2<Nn;m2++) T[m2*132+t] *= invs;
  }
  __syncthreads();
  {
    const int ng_ = t & 15, cg = t >> 4;
    const int an0 = ng_*8;
    for (int pass=0; pass<NPASS; ++pass){
      const int c0 = pass*64 + cg*CPT;
      float av[CPT][8];
      #pragma unroll
      for (int ci2=0;ci2<CPT;ci2++)
        #pragma unroll
        for (int j2=0;j2<8;j2++) av[ci2][j2] = 0.f;
      for (int m2=0;m2<Nn;m2++){
        float tv[8];
        #pragma unroll
        for (int j2=0;j2<8;j2++) tv[j2] = T[m2*132 + an0 + j2];
        #pragma unroll
        for (int ci2=0;ci2<CPT;ci2++){
          const float vv = v[kvoff + (size_t)(c0+ci2)*Nn + m2];
          #pragma unroll
          for (int j2=0;j2<8;j2++) av[ci2][j2] = fmaf(vv, tv[j2], av[ci2][j2]);
        }
      }
      #pragma unroll
      for (int ci2=0;ci2<CPT;ci2++){
        float* op = o + ooff + (size_t)(c0+ci2)*Nn + an0;
        #pragma unroll
        for (int j2=0;j2<8;j2++) if (an0+j2 < Nn) op[j2] = av[ci2][j2];
      }
    }
  }
}

// Spatial mean per (sample, channel). grid=(samples,32).
__global__ __launch_bounds__(128) void mean_kernel(const float* __restrict__ x, float* __restrict__ out)
{
  const int s = blockIdx.x; const int c0 = blockIdx.y*8;
  __shared__ float r[2];
  for (int cc=0; cc<8; ++cc){
    const int c = c0+cc;
    float v = 0.f;
    if (threadIdx.x < Nn) v = x[((size_t)s*Cn + c)*Nn + threadIdx.x];
    #pragma unroll
    for (int o=32;o>0;o>>=1) v += __shfl_down(v, o, 64);
    if ((threadIdx.x & 63) == 0) r[threadIdx.x>>6] = v;
    __syncthreads();
    if (threadIdx.x == 0) out[(size_t)s*Cn + c] = (r[0]+r[1]) * (1.f/Nn);
    __syncthreads();
  }
}

// gate[b,c] = sigmoid( gwT[:,c] . [meanX(b&xm); meanM(b)] + gb[c] )
__global__ __launch_bounds__(256) void gate_kernel(
    const float* __restrict__ meanX, const float* __restrict__ meanM,
    const float* __restrict__ gwT, const float* __restrict__ gb,
    float* __restrict__ gate, int xm)
{
  const int b = blockIdx.x;
  __shared__ float mv[512];
  mv[threadIdx.x]     = meanX[(size_t)(b & xm)*Cn + threadIdx.x];
  mv[256+threadIdx.x] = meanM[(size_t)b*Cn + threadIdx.x];
  __syncthreads();
  float acc = gb[threadIdx.x];
  for (int k2=0;k2<512;k2++) acc = fmaf(gwT[(size_t)k2*256 + threadIdx.x], mv[k2], acc);
  gate[(size_t)b*Cn + threadIdx.x] = 1.f/(1.f+__expf(-acc));
}

// out (+)= msg * gate
__global__ __launch_bounds__(256) void accum_kernel(
    const float* __restrict__ msg, const float* __restrict__ gate,
    float* __restrict__ outs, int init)
{
  const size_t idx = (size_t)blockIdx.x*256 + threadIdx.x;
  if (idx >= SLICEsz) return;
  const size_t t_ = idx / Nn;
  const int c = (int)(t_ & 255);
  const int b = (int)(t_ >> 8);
  const float v = msg[idx] * gate[(size_t)b*Cn + c];
  outs[idx] = init ? v : (outs[idx] + v);
}

// hi = iia*hi + (1-iia)*outi
__global__ __launch_bounds__(256) void comb_kernel(float* __restrict__ hi,
    const float* __restrict__ outi, const float* __restrict__ iia)
{
  const size_t idx = (size_t)blockIdx.x*256 + threadIdx.x;
  if (idx >= SLICEsz) return;
  const float a = *iia;
  hi[idx] = a*hi[idx] + (1.f-a)*outi[idx];
}

// rh = sigmoid(zrq[:,256:512]) * h   (batched: nelem = cn*SLICEsz)
__global__ __launch_bounds__(256) void rh_kernel(const float* __restrict__ zrq,
    const float* __restrict__ h, float* __restrict__ rh, size_t nelem)
{
  const size_t idx = (size_t)blockIdx.x*256 + threadIdx.x;
  if (idx >= nelem) return;
  const int n_ = (int)(idx % Nn);
  const size_t t_ = idx / Nn;
  const int c = (int)(t_ & 255);
  const size_t s = t_ >> 8;
  float r = zrq[(s*512 + 256 + c)*Nn + n_];
  r = 1.f/(1.f+__expf(-r));
  rh[idx] = r*h[idx];
}

// nh = (1-z)*h + z*tanh(hq) + h   (batched)
__global__ __launch_bounds__(256) void nh_kernel(const float* __restrict__ zrq,
    const float* __restrict__ hq, const float* __restrict__ h,
    float* __restrict__ nh, size_t nelem)
{
  const size_t idx = (size_t)blockIdx.x*256 + threadIdx.x;
  if (idx >= nelem) return;
  const int n_ = (int)(idx % Nn);
  const size_t t_ = idx / Nn;
  const int c = (int)(t_ & 255);
  const size_t s = t_ >> 8;
  float z = zrq[(s*512 + c)*Nn + n_];
  z = 1.f/(1.f+__expf(-z));
  const float hv = h[idx];
  nh[idx] = (1.f-z)*hv + z*tanhf(hq[idx]) + hv;
}

// ---------------------------------------------------------------------------
// Host orchestration
// ---------------------------------------------------------------------------
static const int PJ[5][4] = {{1,2,0,0},{0,2,3,0},{0,1,3,4},{1,2,4,0},{2,3,0,0}};
static const int PNP[5]   = {2,3,4,3,2};

extern "C" void kernel_launch(void* const* d_in, const int* in_sizes, int n_in,
                              void* d_out, int out_size, void* d_ws, size_t ws_size,
                              hipStream_t stream)
{
  (void)in_sizes; (void)n_in; (void)out_size;
  const float* x   = (const float*)d_in[0];
  const float* ing = (const float*)d_in[1];
  const float* inb = (const float*)d_in[2];
  const float* iqw = (const float*)d_in[3];
  const float* iqb = (const float*)d_in[4];
  const float* ikw = (const float*)d_in[5];
  const float* ikb = (const float*)d_in[6];
  const float* ivw = (const float*)d_in[7];
  const float* ivb = (const float*)d_in[8];
  const float* iow = (const float*)d_in[9];
  const float* iob = (const float*)d_in[10];
  const float* iong= (const float*)d_in[11];
  const float* ionb= (const float*)d_in[12];
  const float* ia  = (const float*)d_in[13];
  const float* eng = (const float*)d_in[14];
  const float* enb = (const float*)d_in[15];
  const float* rpe = (const float*)d_in[16];
  const float* mw  = (const float*)d_in[17];
  const float* mb  = (const float*)d_in[18];
  const float* eqw = (const float*)d_in[19];
  const float* eqb = (const float*)d_in[20];
  const float* ekw = (const float*)d_in[21];
  const float* ekb = (const float*)d_in[22];
  const float* evw = (const float*)d_in[23];
  const float* evb = (const float*)d_in[24];
  const float* gw  = (const float*)d_in[25];
  const float* gb  = (const float*)d_in[26];
  const float* eow = (const float*)d_in[27];
  const float* eob = (const float*)d_in[28];
  const float* eong= (const float*)d_in[29];
  const float* eonb= (const float*)d_in[30];
  const float* iia = (const float*)d_in[31];
  const float* zrw = (const float*)d_in[32];
  const float* zrb = (const float*)d_in[33];
  const float* hww = (const float*)d_in[34];
  const float* hwb = (const float*)d_in[35];
  const float* ng  = (const float*)d_in[36];
  const float* nbg = (const float*)d_in[37];

  // ---- workspace layout (floats) ----
  float* W = (float*)d_ws;
  size_t off = 0;
  float* h      = W + off; off += FULLsz + 1024;          // persistent state
  float* big    = W + off; off += 6*SLICEsz + 1024;       // qkv / y+kv / zrq / io-out
  float* p2     = W + off; off += 2*SLICEsz + 1024;       // attn out / msg / hq
  float* xsl    = W + off; off += 2*SLICEsz + 1024;       // xn / rh / nh
  float* qsl    = W + off; off += SLA;                    // eq
  float* osl    = W + off; off += SLA;                    // inter accumulation
  float* meanXb = W + off; off += Bn*Cn;
  float* meanM  = W + off; off += 2*Bn*Cn;                // pair-batched
  float* gateb  = W + off; off += 2*Bn*Cn;
  float* bqkv   = W + off; off += 768;                    // concat bias q|k|v
  float* bekv   = W + off; off += 512;                    // concat bias ek|ev
  float* gwT    = W + off; off += 512*256;                // transposed gate weight
  // bf16 weight buffers (shorts), allocated on float boundary
  short* WB = (short*)(W + off);
  size_t so = 0;
  short* iqB = WB + so; so += (size_t)256*9*256;          // iq|ik|iv contiguous
  short* ikB = WB + so; so += (size_t)256*9*256;
  short* ivB = WB + so; so += (size_t)256*9*256;
  short* ioB = WB + so; so += (size_t)256*9*256;
  short* eqB = WB + so; so += (size_t)256*9*256;
  short* ekB = WB + so; so += (size_t)256*9*256;          // ek|ev contiguous
  short* evB = WB + so; so += (size_t)256*9*256;
  short* eoB = WB + so; so += (size_t)256*9*256;
  short* mB_ = WB + so; so += (size_t)256*9*384;
  short* zrB = WB + so; so += (size_t)512*9*512;
  short* hwB = WB + so; so += (size_t)256*9*512;
  off += (so + 1) / 2;
  if (ws_size < off * sizeof(float)) return;              // diagnostic guard

  float* hi = (float*)d_out;                              // full arena: intra out / comb

  hipMemcpyAsync(h, x, FULLsz*sizeof(float), hipMemcpyDeviceToDevice, stream);
  hipMemcpyAsync(bqkv,     iqb, 256*sizeof(float), hipMemcpyDeviceToDevice, stream);
  hipMemcpyAsync(bqkv+256, ikb, 256*sizeof(float), hipMemcpyDeviceToDevice, stream);
  hipMemcpyAsync(bqkv+512, ivb, 256*sizeof(float), hipMemcpyDeviceToDevice, stream);
  hipMemcpyAsync(bekv,     ekb, 256*sizeof(float), hipMemcpyDeviceToDevice, stream);
  hipMemcpyAsync(bekv+256, evb, 256*sizeof(float), hipMemcpyDeviceToDevice, stream);

  // ---- weight prep (once per call) ----
  wprep_kernel<<<dim3(256,9),128,0,stream>>>(iqw, iqB, 256, 256);
  wprep_kernel<<<dim3(256,9),128,0,stream>>>(ikw, ikB, 256, 256);
  wprep_kernel<<<dim3(256,9),128,0,stream>>>(ivw, ivB, 256, 256);
  wprep_kernel<<<dim3(256,9),128,0,stream>>>(iow, ioB, 256, 256);
  wprep_kernel<<<dim3(256,9),128,0,stream>>>(eqw, eqB, 256, 256);
  wprep_kernel<<<dim3(256,9),128,0,stream>>>(ekw, ekB, 256, 256);
  wprep_kernel<<<dim3(256,9),128,0,stream>>>(evw, evB, 256, 256);
  wprep_kernel<<<dim3(256,9),128,0,stream>>>(eow, eoB, 256, 256);
  wprep_kernel<<<dim3(256,9),128,0,stream>>>(mw,  mB_, 259, 384);
  wprep_kernel<<<dim3(512,9),128,0,stream>>>(zrw, zrB, 512, 512);
  wprep_kernel<<<dim3(256,9),128,0,stream>>>(hww, hwB, 512, 512);
  gwt_kernel<<<512,256,0,stream>>>(gw, gwT);

  const int gridSlc = (int)(SLICEsz / 256);   // 15,488 exact
  const float4 f4z = {0.f,0.f,0.f,0.f};

  // regular conv: NS_ = sample-batch multiplier (contiguous inputs/outputs)
  #define CONV(inA_, inB_, Cin_, Cinp_, Cout_, wb_, bi_, out_, NS_)              \
    conv_mfma_kernel<<<dim3(Bn*(NS_), (Cout_)/128), 512, 0, stream>>>(           \
        inA_, nullptr, inB_, 256, Cin_, Cinp_, Cout_, wb_, bi_, out_,            \
        0, f4z, nullptr, nullptr)

  for (int it = 0; it < NITERn; ++it){
    // ---------------- intra_all (slice-pairs) ----------------
    for (int s0 = 0; s0 < Sn; s0 += 2){
      const int cn = (Sn - s0 >= 2) ? 2 : 1;
      const float* hs = h + (size_t)s0*SLICEsz;
      ln_kernel<<<Bn*cn,256,0,stream>>>(hs, ing, inb, xsl, nullptr, nullptr, 0);
      CONV(xsl, nullptr, 256, 256, 768, iqB, bqkv, big, cn);                     // q|k|v
      attn_kernel<256,4,4><<<Bn*cn,256,0,stream>>>(big, big + (size_t)256*Nn,
                                                big + (size_t)512*Nn, p2,
                                                768, 768, 256, 0x7fffffff);
      CONV(p2, nullptr, 256, 256, 256, ioB, iob, big, cn);                       // io-out
      ln_kernel<<<Bn*cn,256,0,stream>>>(big, iong, ionb, hi + (size_t)s0*SLICEsz, ia, xsl, 1);
    }

    // ---------------- inter (per i, pair-chunks of 2) ----------------
    for (int i = 0; i < Sn; ++i){
      ln_kernel<<<Bn,256,0,stream>>>(h + (size_t)i*SLICEsz, eng, enb, xsl, nullptr, nullptr, 0);
      CONV(xsl, nullptr, 256, 256, 256, eqB, eqb, qsl, 1);
      mean_kernel<<<dim3(Bn,32),128,0,stream>>>(xsl, meanXb);
      const int np = PNP[i];
      int done = 0; int first = 1;
      while (done < np){
        const int cn = (np - done >= 2) ? 2 : 1;
        const int j0 = PJ[i][done];
        const int j1 = PJ[i][done + cn - 1];
        const float4 tcs = { (i < j0) ? 1.f : -1.f, fabsf((float)(i - j0)) * 0.5f,
                             (i < j1) ? 1.f : -1.f, fabsf((float)(i - j1)) * 0.5f };
        const int r0 = (((i - j0 + 1) % 4) + 4) % 4;
        const int r1 = (((i - j1 + 1) % 4) + 4) % 4;
        // y (pair-batched m-conv) -> big[0 : cn*S)
        conv_mfma_kernel<<<dim3(Bn*cn,2),512,0,stream>>>(
            h + (size_t)j0*SLICEsz, h + (size_t)j1*SLICEsz, nullptr,
            256, 259, 384, 256, mB_, mb, big,
            1, tcs, rpe + (size_t)r0*Nn, rpe + (size_t)r1*Nn);
        // k|v -> big[2S : 2S+2cn*S)
        CONV(big, nullptr, 256, 256, 512, ekB, bekv, big + 2*SLICEsz, cn);
        // msg_raw -> big[0 : cn*S)  (y dead)
        attn_kernel<32,2,1><<<Bn*cn*HEADSn,256,0,stream>>>(
            qsl, big + 2*SLICEsz, big + 2*SLICEsz + (size_t)256*Nn, big,
            256, 512, 256, 127);
        // eo -> p2 ; LN(relu) in place
        CONV(big, nullptr, 256, 256, 256, eoB, eob, p2, cn);
        ln_kernel<<<Bn*cn,256,0,stream>>>(p2, eong, eonb, p2, nullptr, nullptr, 1);
        mean_kernel<<<dim3(Bn*cn,32),128,0,stream>>>(p2, meanM);
        gate_kernel<<<Bn*cn,256,0,stream>>>(meanXb, meanM, gwT, gb, gateb, 127);
        accum_kernel<<<gridSlc,256,0,stream>>>(p2, gateb, osl, first);
        if (cn == 2)
          accum_kernel<<<gridSlc,256,0,stream>>>(p2 + SLICEsz, gateb + Bn*Cn, osl, 0);
        first = 0; done += cn;
      }
      comb_kernel<<<gridSlc,256,0,stream>>>(hi + (size_t)i*SLICEsz, osl, iia);   // hi=comb
    }

    // ---------------- GRU + final LN (slice-pairs) ----------------
    for (int s0 = 0; s0 < Sn; s0 += 2){
      const int cn = (Sn - s0 >= 2) ? 2 : 1;
      const float* hs = h + (size_t)s0*SLICEsz;
      float* cs = hi + (size_t)s0*SLICEsz;   // comb
      CONV(cs, hs, 512, 512, 512, zrB, zrb, big, cn);                            // zrq
      rh_kernel<<<gridSlc*cn,256,0,stream>>>(big, hs, xsl, (size_t)cn*SLICEsz);  // xsl = r*h
      CONV(cs, xsl, 512, 512, 256, hwB, hwb, p2, cn);                            // hq
      nh_kernel<<<gridSlc*cn,256,0,stream>>>(big, p2, hs, xsl, (size_t)cn*SLICEsz);
      float* dst = (it == NITERn-1) ? cs : (float*)hs;
      ln_kernel<<<Bn*cn,256,0,stream>>>(xsl, ng, nbg, dst, nullptr, nullptr, 0);
    }
  }
  #undef CONV
}

// Round 8
// 13725.443 us; speedup vs baseline: 2.4523x; 1.0382x over previous
//
#include <hip/hip_runtime.h>
#include <cstdint>
#include <cstddef>
#include <cmath>

// ---------------------------------------------------------------------------
// LiveSAL round 10: R8 (verified 14.25ms) + cross-i pair chunking (7 chunks,
// all cn=2) using a 2-slot q/meanX cache with lazy per-slice preamble, and
// comb fused into accum (hi = a*hi + (1-a)*sum incrementally; osl dropped).
// Memory footprint kept at R8's verified ~290MB. Conv/LN/attn inner code
// verbatim R8.
// ---------------------------------------------------------------------------

#define Sn 5
#define Bn 128
#define Cn 256
#define Nn 121          // 11*11
#define HEADSn 8
#define NITERn 2
#define EPSf 1e-5f
#define SCALEf 0.0625f  // 256^-0.5
#define CHWn (Cn*Nn)    // 30976

static const size_t SLICEsz = (size_t)Bn*CHWn;       // 3,964,928 floats
static const size_t FULLsz  = (size_t)Sn*SLICEsz;    // 19,824,640 floats

typedef __attribute__((ext_vector_type(8))) short short8;
typedef __attribute__((ext_vector_type(4))) float f32x4;

static __device__ __forceinline__ short f2bf(float f){
  union { float f; unsigned u; } x; x.f = f;
  unsigned r = (x.u + 0x7FFFu + ((x.u >> 16) & 1u)) >> 16;   // RNE
  return (short)r;
}

// ---------------------------------------------------------------------------
// Weight prep: fp32 [Cout][Cin][3][3] -> bf16 fragment-ordered
//   AW[coH][grp][tap][kc][ms][lane][8],  lane = quad*16+l15
// ---------------------------------------------------------------------------
__global__ __launch_bounds__(128) void wprep_kernel(
    const float* __restrict__ w, short* __restrict__ o, int Cin, int Cinp)
{
  const int co = blockIdx.x, tap = blockIdx.y;
  const int G = Cinp >> 7;
  const int coH = co >> 6, ms = (co >> 4) & 3, l15 = co & 15;
  const float* wrow = w + (size_t)co*Cin*9 + tap;
  short* obase = o + (size_t)coH*G*73728 + (size_t)tap*8192 + ms*512 + l15*8;
  for (int ci = threadIdx.x; ci < Cinp; ci += 128){
    const int grp = ci >> 7, kc = (ci >> 5) & 3, quad = (ci >> 3) & 3, e = ci & 7;
    const short val = (ci < Cin) ? f2bf(wrow[(size_t)ci*9]) : (short)0;
    obase[(size_t)grp*73728 + kc*2048 + quad*128 + e] = val;
  }
}

// gw [256][512] fp32 -> gwT [512][256]
__global__ __launch_bounds__(256) void gwt_kernel(
    const float* __restrict__ gw, float* __restrict__ gwT)
{
  const int k = blockIdx.x, c = threadIdx.x;
  gwT[(size_t)k*256 + c] = gw[(size_t)c*512 + k];
}

// ---------------------------------------------------------------------------
// MFMA conv3x3, pad=1, 11x11. blockIdx.x = sample (possibly batched);
// block = 8 waves (512 thr), block tile 128co x 128px, wave tile 64co x 32px.
// A: fragment-ordered global bf16 (coalesced 1KB loads).
// B: staged per 128-ci group into LDS [px][ci] bf16 (stride 136, rows
//    121..127 zero sentinel) -- R5-verified synchronous staging.
// inA1 != nullptr selects pair-batched m-conv mode: samples 0..127 use inA,
// 128..255 use inA1, with per-pair tc/rpe extras.
// ---------------------------------------------------------------------------
__global__ __launch_bounds__(512) void conv_mfma_kernel(
    const float* __restrict__ inA, const float* __restrict__ inA1,
    const float* __restrict__ inB,
    int cinA, int Cin, int Cinp, int Cout,
    const short* __restrict__ wbf, const float* __restrict__ bias,
    float* __restrict__ out,
    int mMode, float4 tcs,
    const float* __restrict__ rp0, const float* __restrict__ rp1)
{
  __shared__ short Xs[128*136];
  const int samp = blockIdx.x;
  const int coB  = blockIdx.y * 128;
  const int t    = threadIdx.x;
  const int lane = t & 63;
  const int wv   = t >> 6;       // 0..7
  const int wy   = wv >> 2;      // co 64-half within block
  const int wx   = wv & 3;       // px 32-quarter within block
  const int l15  = lane & 15;
  const int quad = lane >> 4;
  const int G    = Cinp >> 7;

  const int pr = samp >> 7;      // pair select (only used when inA1 != null)
  const float* baseA = inA1 ? ((pr ? inA1 : inA) + (size_t)(samp & 127)*cinA*Nn)
                            : (inA + (size_t)samp*(size_t)cinA*Nn);
  const float* baseB = inB ? inB + (size_t)samp*(size_t)(Cin-cinA)*Nn : nullptr;
  const float mtc0 = pr ? tcs.z : tcs.x;
  const float mtc1 = pr ? tcs.w : tcs.y;
  const float* rp  = pr ? rp1 : rp0;

  int nout[2], py[2], pxx[2];
  #pragma unroll
  for (int ns = 0; ns < 2; ++ns){
    nout[ns] = wx*32 + ns*16 + l15;
    py[ns]  = nout[ns] / 11;
    pxx[ns] = nout[ns] % 11;
  }

  f32x4 acc[4][2];
  #pragma unroll
  for (int ms = 0; ms < 4; ++ms)
    #pragma unroll
    for (int ns = 0; ns < 2; ++ns) acc[ms][ns] = (f32x4){0.f,0.f,0.f,0.f};

  // per-wave weight base
  const short* wgbase = wbf + (size_t)(blockIdx.y*2 + wy)*G*73728 + lane*8;

  const int ngrp = (Cin + 127) >> 7;
  for (int grp = 0; grp < ngrp; ++grp){
    __syncthreads();
    // ---- stage 128 ci x 128 px into LDS as bf16 [px][ci] (R5 verbatim) ----
    for (int e = t; e < 128*128; e += 512){
      const int px = e & 127, cil = e >> 7;
      const int ci = grp*128 + cil;
      float v = 0.f;
      if (px < Nn && ci < Cin){
        if (mMode && ci >= 256)
          v = (ci == 256) ? mtc0 : (ci == 257) ? mtc1 : rp[px];
        else if (ci < cinA) v = baseA[(size_t)ci*Nn + px];
        else                v = baseB[(size_t)(ci-cinA)*Nn + px];
      }
      Xs[px*136 + cil] = f2bf(v);
    }
    __syncthreads();

    const int rem = Cin - grp*128;
    const short* wgrp = wgbase + (size_t)grp*73728;

    if (rem >= 128){
      for (int tap = 0; tap < 9; ++tap){
        const int dy = tap/3 - 1, dx = tap%3 - 1;
        int pp[2];
        #pragma unroll
        for (int ns = 0; ns < 2; ++ns){
          const int yy = py[ns] + dy, xx = pxx[ns] + dx;
          const bool ok = (nout[ns] < Nn) && yy >= 0 && yy < 11 && xx >= 0 && xx < 11;
          pp[ns] = ok ? yy*11 + xx : Nn;   // row 121 = zero sentinel
        }
        const short* wb = wgrp + tap*8192;
        #pragma unroll
        for (int kc = 0; kc < 4; ++kc){
          short8 a[4], b[2];
          #pragma unroll
          for (int ms = 0; ms < 4; ++ms)
            a[ms] = *(const short8*)(wb + kc*2048 + ms*512);
          #pragma unroll
          for (int ns = 0; ns < 2; ++ns)
            b[ns] = *(const short8*)(&Xs[pp[ns]*136 + kc*32 + quad*8]);
          #pragma unroll
          for (int ms = 0; ms < 4; ++ms)
            #pragma unroll
            for (int ns = 0; ns < 2; ++ns)
              acc[ms][ns] = __builtin_amdgcn_mfma_f32_16x16x32_bf16(
                                a[ms], b[ns], acc[ms][ns], 0, 0, 0);
        }
      }
    } else {
      const int nkc = (rem + 31) >> 5;
      for (int tap = 0; tap < 9; ++tap){
        const int dy = tap/3 - 1, dx = tap%3 - 1;
        int pp[2];
        #pragma unroll
        for (int ns = 0; ns < 2; ++ns){
          const int yy = py[ns] + dy, xx = pxx[ns] + dx;
          const bool ok = (nout[ns] < Nn) && yy >= 0 && yy < 11 && xx >= 0 && xx < 11;
          pp[ns] = ok ? yy*11 + xx : Nn;
        }
        const short* wb = wgrp + tap*8192;
        for (int kc = 0; kc < nkc; ++kc){
          short8 a[4], b[2];
          #pragma unroll
          for (int ms = 0; ms < 4; ++ms)
            a[ms] = *(const short8*)(wb + kc*2048 + ms*512);
          #pragma unroll
          for (int ns = 0; ns < 2; ++ns)
            b[ns] = *(const short8*)(&Xs[pp[ns]*136 + kc*32 + quad*8]);
          #pragma unroll
          for (int ms = 0; ms < 4; ++ms)
            #pragma unroll
            for (int ns = 0; ns < 2; ++ns)
              acc[ms][ns] = __builtin_amdgcn_mfma_f32_16x16x32_bf16(
                                a[ms], b[ns], acc[ms][ns], 0, 0, 0);
        }
      }
    }
  }

  // ---- epilogue: C layout col=lane&15 (n), row=quad*4+r (m) ----
  #pragma unroll
  for (int ms = 0; ms < 4; ++ms)
    #pragma unroll
    for (int ns = 0; ns < 2; ++ns){
      const int n = nout[ns];
      if (n < Nn){
        const int mbase = coB + wy*64 + ms*16 + quad*4;
        #pragma unroll
        for (int r = 0; r < 4; ++r)
          out[((size_t)samp*Cout + mbase + r)*Nn + n] = acc[ms][ns][r] + bias[mbase + r];
      }
    }
}

// ---------------------------------------------------------------------------
// LayerNorm over (C,H,W) per sample. out = alpha*maybe_relu(LN(x)*g+b)+addend
// ---------------------------------------------------------------------------
__global__ __launch_bounds__(256) void ln_kernel(
    const float* __restrict__ x, const float* __restrict__ g, const float* __restrict__ bb,
    float* __restrict__ out, const float* __restrict__ alpha,
    const float* __restrict__ addend, int relu)
{
  const size_t base = (size_t)blockIdx.x * CHWn;
  const f32x4* xs = (const f32x4*)(x + base);
  const int NV = CHWn/4;   // 7744
  float sum = 0.f, ss = 0.f;
  for (int i = threadIdx.x; i < NV; i += 256){
    f32x4 v = xs[i];
    sum += v.x + v.y + v.z + v.w;
    ss  += v.x*v.x + v.y*v.y + v.z*v.z + v.w*v.w;
  }
  #pragma unroll
  for (int o = 32; o > 0; o >>= 1){ sum += __shfl_down(sum, o, 64); ss += __shfl_down(ss, o, 64); }
  __shared__ float r1[4], r2[4];
  const int wid = threadIdx.x >> 6;
  if ((threadIdx.x & 63) == 0){ r1[wid] = sum; r2[wid] = ss; }
  __syncthreads();
  sum = r1[0]+r1[1]+r1[2]+r1[3];
  ss  = r2[0]+r2[1]+r2[2]+r2[3];
  const float mean = sum * (1.f/CHWn);
  const float var  = ss * (1.f/CHWn) - mean*mean;
  const float inv  = rsqrtf(var + EPSf);
  const float a = alpha ? *alpha : 1.f;
  const f32x4* gv = (const f32x4*)g;
  const f32x4* bv = (const f32x4*)bb;
  const f32x4* av = addend ? (const f32x4*)(addend + base) : nullptr;
  f32x4* ov = (f32x4*)(out + base);
  for (int i = threadIdx.x; i < NV; i += 256){
    f32x4 v = (xs[i] - mean) * inv * gv[i] + bv[i];
    if (relu){ v.x=fmaxf(v.x,0.f); v.y=fmaxf(v.y,0.f); v.z=fmaxf(v.z,0.f); v.w=fmaxf(v.w,0.f); }
    v *= a;
    if (av) v += av[i];
    ov[i] = v;
  }
}

// ---------------------------------------------------------------------------
// Fused attention per (sample, head). qsel0 < 0: q indexed by samp (stride
// qs). Else: 2-slot q cache select — half 0 (samp<128) uses slot qsel0,
// half 1 uses slot qsel1; q layout [slot][b][256ch][Nn].
// ---------------------------------------------------------------------------
template<int HDt, int CPT, int NPASS>
__global__ __launch_bounds__(256) void attn_kernel(
    const float* __restrict__ q, const float* __restrict__ k, const float* __restrict__ v,
    float* __restrict__ o, int qs, int ks, int os, int qsel0, int qsel1)
{
  __shared__ float T[Nn*132];
  const int nh_ = Cn / HDt;
  const int samp = blockIdx.x / nh_;
  const int hh = blockIdx.x % nh_;
  size_t qoff;
  if (qsel0 < 0) qoff = ((size_t)samp*qs + hh*HDt)*Nn;
  else {
    const int slot = (samp >> 7) ? qsel1 : qsel0;
    qoff = ((size_t)slot*Bn + (samp & 127))*(size_t)CHWn + (size_t)hh*HDt*Nn;
  }
  const size_t kvoff = ((size_t)samp*ks + hh*HDt)*Nn;
  const size_t ooff  = ((size_t)samp*os + hh*HDt)*Nn;
  const int t = threadIdx.x;
  {
    const int tn = t >> 4, tm = t & 15;
    const int n0 = tn*8, m0 = tm*8;
    float acc[8][8];
    #pragma unroll
    for (int a2=0;a2<8;a2++)
      #pragma unroll
      for (int b2=0;b2<8;b2++) acc[a2][b2] = 0.f;
    const float* qp = q + qoff + n0;
    const float* kp = k + kvoff + m0;
    #pragma unroll 2
    for (int d=0; d<HDt; ++d){
      float qv[8], kv[8];
      #pragma unroll
      for (int j2=0;j2<8;j2++){ qv[j2] = qp[d*Nn + j2]; kv[j2] = kp[d*Nn + j2]; }
      #pragma unroll
      for (int a2=0;a2<8;a2++)
        #pragma unroll
        for (int b2=0;b2<8;b2++) acc[a2][b2] = fmaf(qv[a2], kv[b2], acc[a2][b2]);
    }
    #pragma unroll
    for (int b2=0;b2<8;b2++){
      const int m = m0 + b2;
      if (m < Nn){
        #pragma unroll
        for (int a2=0;a2<8;a2++) T[m*132 + n0 + a2] = acc[a2][b2] * SCALEf;
      }
    }
  }
  __syncthreads();
  if (t < Nn){
    float mx = -1e30f;
    for (int m2=0;m2<Nn;m2++) mx = fmaxf(mx, T[m2*132+t]);
    float sum = 0.f;
    for (int m2=0;m2<Nn;m2++){ float e = __expf(T[m2*132+t]-mx); sum += e; T[m2*132+t] = e; }
    const float invs = 1.f/sum;
    for (int m2=0;m2<Nn;m2++) T[m2*132+t] *= invs;
  }
  __syncthreads();
  {
    const int ng_ = t & 15, cg = t >> 4;
    const int an0 = ng_*8;
    for (int pass=0; pass<NPASS; ++pass){
      const int c0 = pass*64 + cg*CPT;
      float av[CPT][8];
      #pragma unroll
      for (int ci2=0;ci2<CPT;ci2++)
        #pragma unroll
        for (int j2=0;j2<8;j2++) av[ci2][j2] = 0.f;
      for (int m2=0;m2<Nn;m2++){
        float tv[8];
        #pragma unroll
        for (int j2=0;j2<8;j2++) tv[j2] = T[m2*132 + an0 + j2];
        #pragma unroll
        for (int ci2=0;ci2<CPT;ci2++){
          const float vv = v[kvoff + (size_t)(c0+ci2)*Nn + m2];
          #pragma unroll
          for (int j2=0;j2<8;j2++) av[ci2][j2] = fmaf(vv, tv[j2], av[ci2][j2]);
        }
      }
      #pragma unroll
      for (int ci2=0;ci2<CPT;ci2++){
        float* op = o + ooff + (size_t)(c0+ci2)*Nn + an0;
        #pragma unroll
        for (int j2=0;j2<8;j2++) if (an0+j2 < Nn) op[j2] = av[ci2][j2];
      }
    }
  }
}

// Spatial mean per (sample, channel). grid=(samples,32).
__global__ __launch_bounds__(128) void mean_kernel(const float* __restrict__ x, float* __restrict__ out)
{
  const int s = blockIdx.x; const int c0 = blockIdx.y*8;
  __shared__ float r[2];
  for (int cc=0; cc<8; ++cc){
    const int c = c0+cc;
    float v = 0.f;
    if (threadIdx.x < Nn) v = x[((size_t)s*Cn + c)*Nn + threadIdx.x];
    #pragma unroll
    for (int o=32;o>0;o>>=1) v += __shfl_down(v, o, 64);
    if ((threadIdx.x & 63) == 0) r[threadIdx.x>>6] = v;
    __syncthreads();
    if (threadIdx.x == 0) out[(size_t)s*Cn + c] = (r[0]+r[1]) * (1.f/Nn);
    __syncthreads();
  }
}

// gate[b,c] = sigmoid( gwT[:,c] . [meanX(slot xi, b&127); meanM(b)] + gb[c] )
__global__ __launch_bounds__(256) void gate_kernel(
    const float* __restrict__ meanX, const float* __restrict__ meanM,
    const float* __restrict__ gwT, const float* __restrict__ gb,
    float* __restrict__ gate, int xi0, int xi1)
{
  const int b = blockIdx.x;
  const int xi = (b >> 7) ? xi1 : xi0;
  __shared__ float mv[512];
  mv[threadIdx.x]     = meanX[((size_t)xi*Bn + (b & 127))*Cn + threadIdx.x];
  mv[256+threadIdx.x] = meanM[(size_t)b*Cn + threadIdx.x];
  __syncthreads();
  float acc = gb[threadIdx.x];
  for (int k2=0;k2<512;k2++) acc = fmaf(gwT[(size_t)k2*256 + threadIdx.x], mv[k2], acc);
  gate[(size_t)b*Cn + threadIdx.x] = 1.f/(1.f+__expf(-acc));
}

// Fused accum+comb: init: hi = a*hi + (1-a)*msg*gate ; else: hi += (1-a)*msg*gate
__global__ __launch_bounds__(256) void accum_kernel(
    const float* __restrict__ msg, const float* __restrict__ gate,
    float* __restrict__ hi, const float* __restrict__ iia, int init)
{
  const size_t idx = (size_t)blockIdx.x*256 + threadIdx.x;
  if (idx >= SLICEsz) return;
  const size_t t_ = idx / Nn;
  const int c = (int)(t_ & 255);
  const int b = (int)(t_ >> 8);
  const float a = *iia;
  const float w = (1.f - a) * msg[idx] * gate[(size_t)b*Cn + c];
  hi[idx] = init ? (a*hi[idx] + w) : (hi[idx] + w);
}

// rh = sigmoid(zrq[:,256:512]) * h   (batched: nelem = cn*SLICEsz)
__global__ __launch_bounds__(256) void rh_kernel(const float* __restrict__ zrq,
    const float* __restrict__ h, float* __restrict__ rh, size_t nelem)
{
  const size_t idx = (size_t)blockIdx.x*256 + threadIdx.x;
  if (idx >= nelem) return;
  const int n_ = (int)(idx % Nn);
  const size_t t_ = idx / Nn;
  const int c = (int)(t_ & 255);
  const size_t s = t_ >> 8;
  float r = zrq[(s*512 + 256 + c)*Nn + n_];
  r = 1.f/(1.f+__expf(-r));
  rh[idx] = r*h[idx];
}

// nh = (1-z)*h + z*tanh(hq) + h   (batched)
__global__ __launch_bounds__(256) void nh_kernel(const float* __restrict__ zrq,
    const float* __restrict__ hq, const float* __restrict__ h,
    float* __restrict__ nh, size_t nelem)
{
  const size_t idx = (size_t)blockIdx.x*256 + threadIdx.x;
  if (idx >= nelem) return;
  const int n_ = (int)(idx % Nn);
  const size_t t_ = idx / Nn;
  const int c = (int)(t_ & 255);
  const size_t s = t_ >> 8;
  float z = zrq[(s*512 + c)*Nn + n_];
  z = 1.f/(1.f+__expf(-z));
  const float hv = h[idx];
  nh[idx] = (1.f-z)*hv + z*tanhf(hq[idx]) + hv;
}

// ---------------------------------------------------------------------------
// Host orchestration
// ---------------------------------------------------------------------------
// Global pair list (i-ordered; per-i j order matches reference PJ order)
static const int PIg[14] = {0,0,1,1,1,2,2,2,2,3,3,3,4,4};
static const int PJg[14] = {1,2,0,2,3,0,1,3,4,1,2,4,2,3};
static const int FIRSTP[5] = {0,2,5,9,12};

extern "C" void kernel_launch(void* const* d_in, const int* in_sizes, int n_in,
                              void* d_out, int out_size, void* d_ws, size_t ws_size,
                              hipStream_t stream)
{
  (void)in_sizes; (void)n_in; (void)out_size;
  const float* x   = (const float*)d_in[0];
  const float* ing = (const float*)d_in[1];
  const float* inb = (const float*)d_in[2];
  const float* iqw = (const float*)d_in[3];
  const float* iqb = (const float*)d_in[4];
  const float* ikw = (const float*)d_in[5];
  const float* ikb = (const float*)d_in[6];
  const float* ivw = (const float*)d_in[7];
  const float* ivb = (const float*)d_in[8];
  const float* iow = (const float*)d_in[9];
  const float* iob = (const float*)d_in[10];
  const float* iong= (const float*)d_in[11];
  const float* ionb= (const float*)d_in[12];
  const float* ia  = (const float*)d_in[13];
  const float* eng = (const float*)d_in[14];
  const float* enb = (const float*)d_in[15];
  const float* rpe = (const float*)d_in[16];
  const float* mw  = (const float*)d_in[17];
  const float* mb  = (const float*)d_in[18];
  const float* eqw = (const float*)d_in[19];
  const float* eqb = (const float*)d_in[20];
  const float* ekw = (const float*)d_in[21];
  const float* ekb = (const float*)d_in[22];
  const float* evw = (const float*)d_in[23];
  const float* evb = (const float*)d_in[24];
  const float* gw  = (const float*)d_in[25];
  const float* gb  = (const float*)d_in[26];
  const float* eow = (const float*)d_in[27];
  const float* eob = (const float*)d_in[28];
  const float* eong= (const float*)d_in[29];
  const float* eonb= (const float*)d_in[30];
  const float* iia = (const float*)d_in[31];
  const float* zrw = (const float*)d_in[32];
  const float* zrb = (const float*)d_in[33];
  const float* hww = (const float*)d_in[34];
  const float* hwb = (const float*)d_in[35];
  const float* ng  = (const float*)d_in[36];
  const float* nbg = (const float*)d_in[37];

  // ---- workspace layout (floats) — R8-sized (~290MB) ----
  float* W = (float*)d_ws;
  size_t off = 0;
  float* h      = W + off; off += FULLsz + 1024;          // persistent state
  float* big    = W + off; off += 6*SLICEsz + 1024;       // qkv / y+kv / zrq
  float* p2     = W + off; off += 2*SLICEsz + 1024;       // attn out / msg / hq
  float* xsl    = W + off; off += 2*SLICEsz + 1024;       // xn / rh / nh
  float* qsl    = W + off; off += 2*SLICEsz + 1024;       // eq 2-slot cache
  float* meanXb = W + off; off += 2*Bn*Cn;                // meanX 2-slot cache
  float* meanM  = W + off; off += 2*Bn*Cn;
  float* gateb  = W + off; off += 2*Bn*Cn;
  float* bqkv   = W + off; off += 768;                    // concat bias q|k|v
  float* bekv   = W + off; off += 512;                    // concat bias ek|ev
  float* gwT    = W + off; off += 512*256;                // transposed gate weight
  // bf16 weight buffers (shorts), allocated on float boundary
  short* WB = (short*)(W + off);
  size_t so = 0;
  short* iqB = WB + so; so += (size_t)256*9*256;          // iq|ik|iv contiguous
  short* ikB = WB + so; so += (size_t)256*9*256;
  short* ivB = WB + so; so += (size_t)256*9*256;
  short* ioB = WB + so; so += (size_t)256*9*256;
  short* eqB = WB + so; so += (size_t)256*9*256;
  short* ekB = WB + so; so += (size_t)256*9*256;          // ek|ev contiguous
  short* evB = WB + so; so += (size_t)256*9*256;
  short* eoB = WB + so; so += (size_t)256*9*256;
  short* mB_ = WB + so; so += (size_t)256*9*384;
  short* zrB = WB + so; so += (size_t)512*9*512;
  short* hwB = WB + so; so += (size_t)256*9*512;
  off += (so + 1) / 2;
  if (ws_size < off * sizeof(float)) return;              // diagnostic guard

  float* hi = (float*)d_out;                              // full arena: intra out / comb

  hipMemcpyAsync(h, x, FULLsz*sizeof(float), hipMemcpyDeviceToDevice, stream);
  hipMemcpyAsync(bqkv,     iqb, 256*sizeof(float), hipMemcpyDeviceToDevice, stream);
  hipMemcpyAsync(bqkv+256, ikb, 256*sizeof(float), hipMemcpyDeviceToDevice, stream);
  hipMemcpyAsync(bqkv+512, ivb, 256*sizeof(float), hipMemcpyDeviceToDevice, stream);
  hipMemcpyAsync(bekv,     ekb, 256*sizeof(float), hipMemcpyDeviceToDevice, stream);
  hipMemcpyAsync(bekv+256, evb, 256*sizeof(float), hipMemcpyDeviceToDevice, stream);

  // ---- weight prep (once per call) ----
  wprep_kernel<<<dim3(256,9),128,0,stream>>>(iqw, iqB, 256, 256);
  wprep_kernel<<<dim3(256,9),128,0,stream>>>(ikw, ikB, 256, 256);
  wprep_kernel<<<dim3(256,9),128,0,stream>>>(ivw, ivB, 256, 256);
  wprep_kernel<<<dim3(256,9),128,0,stream>>>(iow, ioB, 256, 256);
  wprep_kernel<<<dim3(256,9),128,0,stream>>>(eqw, eqB, 256, 256);
  wprep_kernel<<<dim3(256,9),128,0,stream>>>(ekw, ekB, 256, 256);
  wprep_kernel<<<dim3(256,9),128,0,stream>>>(evw, evB, 256, 256);
  wprep_kernel<<<dim3(256,9),128,0,stream>>>(eow, eoB, 256, 256);
  wprep_kernel<<<dim3(256,9),128,0,stream>>>(mw,  mB_, 259, 384);
  wprep_kernel<<<dim3(512,9),128,0,stream>>>(zrw, zrB, 512, 512);
  wprep_kernel<<<dim3(256,9),128,0,stream>>>(hww, hwB, 512, 512);
  gwt_kernel<<<512,256,0,stream>>>(gw, gwT);

  const int gridSlc = (int)(SLICEsz / 256);   // 15,488 exact
  const float4 f4z = {0.f,0.f,0.f,0.f};

  // regular conv: NS_ = sample-batch multiplier (contiguous inputs/outputs)
  #define CONV(inA_, inB_, Cin_, Cinp_, Cout_, wb_, bi_, out_, NS_)              \
    conv_mfma_kernel<<<dim3(Bn*(NS_), (Cout_)/128), 512, 0, stream>>>(           \
        inA_, nullptr, inB_, 256, Cin_, Cinp_, Cout_, wb_, bi_, out_,            \
        0, f4z, nullptr, nullptr)

  // per-slice inter preamble: xn -> q(slot i&1) + meanX(slot i&1); cn slices
  #define PREAMBLE(i_, cn_)                                                      \
    do {                                                                          \
      ln_kernel<<<Bn*(cn_),256,0,stream>>>(h + (size_t)(i_)*SLICEsz, eng, enb,    \
                                           xsl, nullptr, nullptr, 0);             \
      CONV(xsl, nullptr, 256, 256, 256, eqB, eqb,                                 \
           qsl + (size_t)((i_)&1)*SLICEsz, cn_);                                  \
      mean_kernel<<<dim3(Bn*(cn_),32),128,0,stream>>>(xsl,                        \
           meanXb + (size_t)((i_)&1)*Bn*Cn);                                      \
    } while (0)

  for (int it = 0; it < NITERn; ++it){
    // ---------------- intra_all (slice-pairs) ----------------
    for (int s0 = 0; s0 < Sn; s0 += 2){
      const int cn = (Sn - s0 >= 2) ? 2 : 1;
      const float* hs = h + (size_t)s0*SLICEsz;
      ln_kernel<<<Bn*cn,256,0,stream>>>(hs, ing, inb, xsl, nullptr, nullptr, 0);
      CONV(xsl, nullptr, 256, 256, 768, iqB, bqkv, big, cn);                     // q|k|v
      attn_kernel<256,4,4><<<Bn*cn,256,0,stream>>>(big, big + (size_t)256*Nn,
                                                big + (size_t)512*Nn, p2,
                                                768, 768, 256, -1, -1);
      CONV(p2, nullptr, 256, 256, 256, ioB, iob, big, cn);                       // io-out
      ln_kernel<<<Bn*cn,256,0,stream>>>(big, iong, ionb, hi + (size_t)s0*SLICEsz, ia, xsl, 1);
    }

    // ---------------- inter: 7 cross-i pair-chunks (all cn=2) -------------
    // lazy preamble schedule keeps 2-slot q/meanX caches coherent:
    //   pre(0,1) | c0 c1 | pre(2->slot0) | c2 c3 | pre(3->slot1) | c4 c5 |
    //   pre(4->slot0) | c6
    for (int c = 0; c < 7; ++c){
      if (c == 0) PREAMBLE(0, 2);       // slices 0(slot0) + 1(slot1)
      if (c == 2) PREAMBLE(2, 1);       // slice 2 -> slot0 (slice 0 dead)
      if (c == 4) PREAMBLE(3, 1);       // slice 3 -> slot1 (slice 1 dead)
      if (c == 6) PREAMBLE(4, 1);       // slice 4 -> slot0 (slice 2 dead)

      const int p0 = 2*c, p1 = 2*c + 1;
      const int i0 = PIg[p0], j0 = PJg[p0];
      const int i1 = PIg[p1], j1 = PJg[p1];
      const float4 tcs = { (i0 < j0) ? 1.f : -1.f, fabsf((float)(i0 - j0)) * 0.5f,
                           (i1 < j1) ? 1.f : -1.f, fabsf((float)(i1 - j1)) * 0.5f };
      const int r0 = (((i0 - j0 + 1) % 4) + 4) % 4;
      const int r1 = (((i1 - j1 + 1) % 4) + 4) % 4;
      // y (pair-batched m-conv) -> big[0 : 2S)
      conv_mfma_kernel<<<dim3(Bn*2,2),512,0,stream>>>(
          h + (size_t)j0*SLICEsz, h + (size_t)j1*SLICEsz, nullptr,
          256, 259, 384, 256, mB_, mb, big,
          1, tcs, rpe + (size_t)r0*Nn, rpe + (size_t)r1*Nn);
      // k|v -> big[2S : 6S)
      CONV(big, nullptr, 256, 256, 512, ekB, bekv, big + 2*SLICEsz, 2);
      // msg_raw -> big[0 : 2S)  (y dead); 2-slot q select
      attn_kernel<32,2,1><<<Bn*2*HEADSn,256,0,stream>>>(
          qsl, big + 2*SLICEsz, big + 2*SLICEsz + (size_t)256*Nn, big,
          256, 512, 256, i0 & 1, i1 & 1);
      // eo -> p2 ; LN(relu) in place
      CONV(big, nullptr, 256, 256, 256, eoB, eob, p2, 2);
      ln_kernel<<<Bn*2,256,0,stream>>>(p2, eong, eonb, p2, nullptr, nullptr, 1);
      mean_kernel<<<dim3(Bn*2,32),128,0,stream>>>(p2, meanM);
      gate_kernel<<<Bn*2,256,0,stream>>>(meanXb, meanM, gwT, gb, gateb, i0 & 1, i1 & 1);
      // fused accum+comb straight into hi[i]
      accum_kernel<<<gridSlc,256,0,stream>>>(p2, gateb,
          hi + (size_t)i0*SLICEsz, iia, p0 == FIRSTP[i0]);
      accum_kernel<<<gridSlc,256,0,stream>>>(p2 + SLICEsz, gateb + Bn*Cn,
          hi + (size_t)i1*SLICEsz, iia, p1 == FIRSTP[i1]);
    }

    // ---------------- GRU + final LN (slice-pairs) ----------------
    for (int s0 = 0; s0 < Sn; s0 += 2){
      const int cn = (Sn - s0 >= 2) ? 2 : 1;
      const float* hs = h + (size_t)s0*SLICEsz;
      float* cs = hi + (size_t)s0*SLICEsz;   // comb (accumulated in place)
      CONV(cs, hs, 512, 512, 512, zrB, zrb, big, cn);                            // zrq
      rh_kernel<<<gridSlc*cn,256,0,stream>>>(big, hs, xsl, (size_t)cn*SLICEsz);  // xsl = r*h
      CONV(cs, xsl, 512, 512, 256, hwB, hwb, p2, cn);                            // hq
      nh_kernel<<<gridSlc*cn,256,0,stream>>>(big, p2, hs, xsl, (size_t)cn*SLICEsz);
      float* dst = (it == NITERn-1) ? cs : (float*)hs;
      ln_kernel<<<Bn*cn,256,0,stream>>>(xsl, ng, nbg, dst, nullptr, nullptr, 0);
    }
  }
  #undef PREAMBLE
  #undef CONV
}